// Round 1
// baseline (236.975 us; speedup 1.0000x reference)
//
#include <hip/hip_runtime.h>
#include <cstdint>
#include <cstddef>

// Problem constants
#define NB 4
#define SS 2048
#define DM 1024
#define DH 64
#define MROWS (NB*SS)      // 8192
#define NALL  (2*DH + DM)  // 1152

typedef __attribute__((ext_vector_type(8))) short bf16x8;
typedef __attribute__((ext_vector_type(4))) float f32x4;
typedef __attribute__((ext_vector_type(4))) unsigned short us4;

__device__ __forceinline__ unsigned short f2bf(float f){
  unsigned u = __builtin_bit_cast(unsigned, f);
  u = (u + 0x7fffu + ((u >> 16) & 1u)) >> 16;   // RNE
  return (unsigned short)u;
}
__device__ __forceinline__ float bf2f(unsigned short h){
  unsigned u = ((unsigned)h) << 16;
  return __builtin_bit_cast(float, u);
}
__device__ __forceinline__ f32x4 mfma16(bf16x8 a, bf16x8 b, f32x4 c){
  return __builtin_amdgcn_mfma_f32_16x16x32_bf16(a, b, c, 0, 0, 0);
}

// ---------------- prep: split x into bf16 hi/lo ----------------
__global__ void prep_x_kernel(const float* __restrict__ x,
                              unsigned short* __restrict__ xh,
                              unsigned short* __restrict__ xl){
  const int n4 = MROWS*DM/4;
  for (int i = blockIdx.x*blockDim.x + threadIdx.x; i < n4; i += gridDim.x*blockDim.x){
    float4 v = reinterpret_cast<const float4*>(x)[i];
    float f[4] = {v.x, v.y, v.z, v.w};
    us4 h, lo;
    #pragma unroll
    for (int j = 0; j < 4; ++j){
      unsigned short hh = f2bf(f[j]);
      h[j]  = hh;
      lo[j] = f2bf(f[j] - bf2f(hh));
    }
    reinterpret_cast<us4*>(xh)[i] = h;
    reinterpret_cast<us4*>(xl)[i] = lo;
  }
}

// ---------------- prep: weights (hi for all 1152 rows, lo for first 128) + bias ----------------
__global__ void prep_w_kernel(const float* __restrict__ wq, const float* __restrict__ wk,
                              const float* __restrict__ wv,
                              const float* __restrict__ bq, const float* __restrict__ bk,
                              const float* __restrict__ bv,
                              unsigned short* __restrict__ Whi, unsigned short* __restrict__ Wlo,
                              float* __restrict__ bias_all){
  const int n = NALL*DM;
  for (int i = blockIdx.x*blockDim.x + threadIdx.x; i < n; i += gridDim.x*blockDim.x){
    const int r = i >> 10, c = i & 1023;
    float v;
    if (r < 64)       v = wq[r*1024 + c];
    else if (r < 128) v = wk[(r-64)*1024 + c];
    else              v = wv[(r-128)*1024 + c];
    const unsigned short h = f2bf(v);
    Whi[i] = h;
    if (r < 128) Wlo[i] = f2bf(v - bf2f(h));
    if (i < NALL) bias_all[i] = (i < 64) ? bq[i] : (i < 128) ? bk[i-64] : bv[i-128];
  }
}

// ---------------- QKV GEMM: C[8192,1152] = x @ [WQ;WK;WV]^T ----------------
// 128x128 tile, BK=32, 4 waves (2x2), 16x16x32 bf16 MFMA, global_load_lds width 16.
// ntile 0 (cols 0..127 = Q|K): 3-pass hi/lo accumulation, epilogue splits to Qh/Ql/Kh/Kl bf16.
// ntile 1..8 (V): 1 pass, epilogue writes V transposed: Vt[b][c][s] bf16.
__global__ __launch_bounds__(256) void qkv_gemm_kernel(
    const unsigned short* __restrict__ xh, const unsigned short* __restrict__ xl,
    const unsigned short* __restrict__ Whi, const unsigned short* __restrict__ Wlo,
    const float* __restrict__ bias_all,
    unsigned short* __restrict__ Qh, unsigned short* __restrict__ Ql,
    unsigned short* __restrict__ Kh, unsigned short* __restrict__ Kl,
    unsigned short* __restrict__ Vt)
{
  __shared__ unsigned short tA[128*32];   // 8 KB, linear [row][k] bf16
  __shared__ unsigned short tB[128*32];
  const int bx = blockIdx.x;
  const int mtile = bx & 63;
  const int ntile = bx >> 6;              // 0..8
  const int m0 = mtile*128, n0 = ntile*128;
  const int tid = threadIdx.x;
  const int l = tid & 63, w = tid >> 6;
  const int lr = l >> 4, lc = l & 15;
  const int wr = w >> 1, wc = w & 1;

  f32x4 acc[4][4] = {};

  const int npass = (ntile == 0) ? 3 : 1;
  for (int pass = 0; pass < npass; ++pass){
    const unsigned short* Ab = (pass == 2) ? xl : xh;
    const unsigned short* Bb = (pass == 1) ? Wlo : (Whi + (size_t)n0*DM);
    for (int k0 = 0; k0 < DM; k0 += 32){
      __syncthreads();
      #pragma unroll
      for (int p = 0; p < 2; ++p){
        const int c   = tid + p*256;        // chunk id: 512 x 16B per tile
        const int row = c >> 2, kq = c & 3; // LDS byte c*16 == row*64 + kq*16
        const unsigned short* ga = Ab + ((size_t)(m0+row)*DM + k0 + kq*8);
        const unsigned short* gb = Bb + ((size_t)row*DM     + k0 + kq*8);
        const int lbase = w*1024 + p*4096;  // wave-uniform base; lane offset = lane*16
        __builtin_amdgcn_global_load_lds(
            (const __attribute__((address_space(1))) void*)ga,
            (__attribute__((address_space(3))) void*)((char*)tA + lbase), 16, 0, 0);
        __builtin_amdgcn_global_load_lds(
            (const __attribute__((address_space(1))) void*)gb,
            (__attribute__((address_space(3))) void*)((char*)tB + lbase), 16, 0, 0);
      }
      __syncthreads();
      bf16x8 af[4], bfr[4];
      #pragma unroll
      for (int mi = 0; mi < 4; ++mi){
        const int r = wr*64 + mi*16 + lc;
        af[mi] = *reinterpret_cast<const bf16x8*>((const char*)tA + r*64 + lr*16);
      }
      #pragma unroll
      for (int ni = 0; ni < 4; ++ni){
        const int r = wc*64 + ni*16 + lc;
        bfr[ni] = *reinterpret_cast<const bf16x8*>((const char*)tB + r*64 + lr*16);
      }
      #pragma unroll
      for (int mi = 0; mi < 4; ++mi)
        #pragma unroll
        for (int ni = 0; ni < 4; ++ni)
          acc[mi][ni] = mfma16(af[mi], bfr[ni], acc[mi][ni]);
    }
  }

  // epilogue
  #pragma unroll
  for (int ni = 0; ni < 4; ++ni){
    const int col = n0 + wc*64 + ni*16 + lc;
    const float bias = bias_all[col];
    #pragma unroll
    for (int mi = 0; mi < 4; ++mi){
      const int rowb = m0 + wr*64 + mi*16 + lr*4;   // rows rowb..rowb+3, same batch
      if (ntile > 0){
        const int vc = col - 128;
        const int b  = rowb >> 11;
        const int s  = rowb & 2047;
        us4 pk;
        #pragma unroll
        for (int i = 0; i < 4; ++i) pk[i] = f2bf(acc[mi][ni][i] + bias);
        *reinterpret_cast<us4*>(&Vt[((size_t)b*DM + vc)*SS + s]) = pk;
      } else {
        #pragma unroll
        for (int i = 0; i < 4; ++i){
          const int row = rowb + i;
          const float v = acc[mi][ni][i] + bias;
          const unsigned short h   = f2bf(v);
          const unsigned short lo2 = f2bf(v - bf2f(h));
          if (col < DH){
            Qh[(size_t)row*DH + col] = h;
            Ql[(size_t)row*DH + col] = lo2;
          } else {
            Kh[(size_t)row*DH + col - DH] = h;
            Kl[(size_t)row*DH + col - DH] = lo2;
          }
        }
      }
    }
  }
}

// ---------------- flash attention, causal ----------------
// Block = (q-tile of 32 rows, batch). 8 waves x 64 lanes.
// Per KBLK=256 keys: waves split keys (32 each) for QK^T (hi/lo 3-pass MFMA),
// block softmax via LDS, waves split V columns (128 each) for PV MFMA.
#define QT 32
#define KBLK 256
#define NEGF (-1e30f)

__global__ __launch_bounds__(512) void attn_kernel(
    const unsigned short* __restrict__ Qh, const unsigned short* __restrict__ Ql,
    const unsigned short* __restrict__ Kh, const unsigned short* __restrict__ Kl,
    const unsigned short* __restrict__ Vt, float* __restrict__ out)
{
  __shared__ float Sl[QT][KBLK+1];            // 32.9 KB, padded (stride 257 f32)
  __shared__ unsigned short Pl[QT][KBLK+8];   // 16.5 KB, padded (stride 528 B)
  __shared__ float m_s[QT], l_s[QT], sc_s[QT];

  const int qt = blockIdx.x, b = blockIdx.y;
  const int q0 = qt*QT;
  const int tid = threadIdx.x, l = tid & 63, w = tid >> 6;
  const int lr = l >> 4, lc = l & 15;
  const float L2E = 1.4426950408889634f;

  // Q fragments (A-operand): row = lane&15, k contiguous 8 per lane-group
  bf16x8 qh[2][2], qlo[2][2];
  #pragma unroll
  for (int qi = 0; qi < 2; ++qi)
    #pragma unroll
    for (int ks = 0; ks < 2; ++ks){
      const size_t off = (size_t)(b*SS + q0 + qi*16 + lc)*DH + ks*32 + lr*8;
      qh[qi][ks]  = *reinterpret_cast<const bf16x8*>(&Qh[off]);
      qlo[qi][ks] = *reinterpret_cast<const bf16x8*>(&Ql[off]);
    }

  f32x4 o[2][8] = {};
  if (tid < QT){ m_s[tid] = NEGF; l_s[tid] = 0.f; }
  __syncthreads();

  const int nkb = (q0 + QT - 1)/KBLK + 1;
  const int fullkb = q0 >> 8;   // kb < fullkb are fully unmasked

  for (int kb = 0; kb < nkb; ++kb){
    const int kbase = kb*KBLK;
    const int kw0 = kbase + w*32;

    // K fragments (B-operand): col = lane&15 is the key index, k contiguous
    bf16x8 kh[2][2], kl2[2][2];
    #pragma unroll
    for (int ki = 0; ki < 2; ++ki)
      #pragma unroll
      for (int ks = 0; ks < 2; ++ks){
        const size_t off = (size_t)(b*SS + kw0 + ki*16 + lc)*DH + ks*32 + lr*8;
        kh[ki][ks]  = *reinterpret_cast<const bf16x8*>(&Kh[off]);
        kl2[ki][ks] = *reinterpret_cast<const bf16x8*>(&Kl[off]);
      }

    f32x4 sa[2][2] = {};
    #pragma unroll
    for (int qi = 0; qi < 2; ++qi)
      #pragma unroll
      for (int ki = 0; ki < 2; ++ki)
        #pragma unroll
        for (int ks = 0; ks < 2; ++ks){
          sa[qi][ki] = mfma16(qh[qi][ks],  kh[ki][ks],  sa[qi][ki]);
          sa[qi][ki] = mfma16(qh[qi][ks],  kl2[ki][ks], sa[qi][ki]);
          sa[qi][ki] = mfma16(qlo[qi][ks], kh[ki][ks],  sa[qi][ki]);
        }

    const bool maskblk = (kb >= fullkb);
    #pragma unroll
    for (int qi = 0; qi < 2; ++qi)
      #pragma unroll
      for (int ki = 0; ki < 2; ++ki)
        #pragma unroll
        for (int i = 0; i < 4; ++i){
          const int qrow = qi*16 + lr*4 + i;           // C: row=(l>>4)*4+i
          const int kcol = w*32 + ki*16 + lc;          // C: col=l&15
          float s = sa[qi][ki][i];
          if (maskblk && (kbase + kcol > q0 + qrow)) s = NEGF;
          Sl[qrow][kcol] = s;
        }
    __syncthreads();

    // softmax: wave w owns rows w*4..w*4+3; 64 lanes x 4 elems per row
    #pragma unroll
    for (int rr = 0; rr < 4; ++rr){
      const int r = w*4 + rr;
      const float mold = m_s[r];
      float v0 = Sl[r][l], v1 = Sl[r][l+64], v2 = Sl[r][l+128], v3 = Sl[r][l+192];
      float mt = fmaxf(fmaxf(v0, v1), fmaxf(v2, v3));
      #pragma unroll
      for (int d = 32; d > 0; d >>= 1) mt = fmaxf(mt, __shfl_xor(mt, d));
      const float mnew = fmaxf(mold, mt);
      const float p0 = exp2f((v0 - mnew)*L2E), p1 = exp2f((v1 - mnew)*L2E);
      const float p2 = exp2f((v2 - mnew)*L2E), p3 = exp2f((v3 - mnew)*L2E);
      float sum = (p0 + p1) + (p2 + p3);
      #pragma unroll
      for (int d = 32; d > 0; d >>= 1) sum += __shfl_xor(sum, d);
      Pl[r][l]     = f2bf(p0);
      Pl[r][l+64]  = f2bf(p1);
      Pl[r][l+128] = f2bf(p2);
      Pl[r][l+192] = f2bf(p3);
      if (l == 0){
        const float sc = exp2f((mold - mnew)*L2E);
        sc_s[r] = sc;
        m_s[r]  = mnew;
        l_s[r]  = l_s[r]*sc + sum;
      }
    }
    __syncthreads();

    // rescale running output
    #pragma unroll
    for (int qi = 0; qi < 2; ++qi)
      #pragma unroll
      for (int i = 0; i < 4; ++i){
        const float sc = sc_s[qi*16 + lr*4 + i];
        #pragma unroll
        for (int ci = 0; ci < 8; ++ci) o[qi][ci][i] *= sc;
      }

    // PV: wave w owns columns w*128..w*128+127
    #pragma unroll
    for (int ks2 = 0; ks2 < 8; ++ks2){
      const bf16x8 pa0 = *reinterpret_cast<const bf16x8*>(&Pl[lc][ks2*32 + lr*8]);
      const bf16x8 pa1 = *reinterpret_cast<const bf16x8*>(&Pl[16+lc][ks2*32 + lr*8]);
      #pragma unroll
      for (int ci = 0; ci < 8; ++ci){
        const int c = w*128 + ci*16 + lc;
        const bf16x8 vb = *reinterpret_cast<const bf16x8*>(
            &Vt[((size_t)b*DM + c)*SS + kbase + ks2*32 + lr*8]);
        o[0][ci] = mfma16(pa0, vb, o[0][ci]);
        o[1][ci] = mfma16(pa1, vb, o[1][ci]);
      }
    }
    // next iteration's first barrier orders PV(t) reads of Pl before softmax(t+1) writes
  }

  #pragma unroll
  for (int qi = 0; qi < 2; ++qi)
    #pragma unroll
    for (int i = 0; i < 4; ++i){
      const int qrow = qi*16 + lr*4 + i;
      const float inv = 1.0f / l_s[qrow];
      #pragma unroll
      for (int ci = 0; ci < 8; ++ci){
        out[(size_t)(b*SS + q0 + qrow)*DM + w*128 + ci*16 + lc] = o[qi][ci][i]*inv;
      }
    }
}

// ---------------- launcher ----------------
extern "C" void kernel_launch(void* const* d_in, const int* in_sizes, int n_in,
                              void* d_out, int out_size, void* d_ws, size_t ws_size,
                              hipStream_t stream)
{
  const float* x  = (const float*)d_in[0];
  const float* wq = (const float*)d_in[1];
  const float* bq = (const float*)d_in[2];
  const float* wk = (const float*)d_in[3];
  const float* bk = (const float*)d_in[4];
  const float* wv = (const float*)d_in[5];
  const float* bv = (const float*)d_in[6];
  float* out = (float*)d_out;

  char* ws = (char*)d_ws;
  // ws layout (bytes), all 256-aligned; total ~57.2 MB
  unsigned short* xh  = (unsigned short*)(ws + 0);          // 16,777,216
  unsigned short* xl  = (unsigned short*)(ws + 16777216);   // 16,777,216
  unsigned short* Whi = (unsigned short*)(ws + 33554432);   //  2,359,296
  unsigned short* Wlo = (unsigned short*)(ws + 35913728);   //    262,144
  float* bias_all     = (float*)(ws + 36175872);            //      4,608
  unsigned short* Qh  = (unsigned short*)(ws + 36180480);   //  1,048,576
  unsigned short* Ql  = (unsigned short*)(ws + 37229056);   //  1,048,576
  unsigned short* Kh  = (unsigned short*)(ws + 38277632);   //  1,048,576
  unsigned short* Kl  = (unsigned short*)(ws + 39326208);   //  1,048,576
  unsigned short* Vt  = (unsigned short*)(ws + 40374784);   // 16,777,216

  hipLaunchKernelGGL(prep_x_kernel, dim3(2048), dim3(256), 0, stream, x, xh, xl);
  hipLaunchKernelGGL(prep_w_kernel, dim3(1184), dim3(256), 0, stream,
                     wq, wk, wv, bq, bk, bv, Whi, Wlo, bias_all);
  hipLaunchKernelGGL(qkv_gemm_kernel, dim3(576), dim3(256), 0, stream,
                     xh, xl, Whi, Wlo, bias_all, Qh, Ql, Kh, Kl, Vt);
  hipLaunchKernelGGL(attn_kernel, dim3(64, 4), dim3(512), 0, stream,
                     Qh, Ql, Kh, Kl, Vt, out);
}

// Round 2
// 213.667 us; speedup vs baseline: 1.1091x; 1.1091x over previous
//
#include <hip/hip_runtime.h>
#include <cstdint>
#include <cstddef>

// Problem constants
#define NB 4
#define SS 2048
#define DM 1024
#define DH 64
#define MROWS (NB*SS)      // 8192
#define NALL  (2*DH + DM)  // 1152

typedef __attribute__((ext_vector_type(8))) short bf16x8;
typedef __attribute__((ext_vector_type(4))) float f32x4;
typedef __attribute__((ext_vector_type(4))) unsigned short us4;

__device__ __forceinline__ unsigned short f2bf(float f){
  unsigned u = __builtin_bit_cast(unsigned, f);
  u = (u + 0x7fffu + ((u >> 16) & 1u)) >> 16;   // RNE
  return (unsigned short)u;
}
__device__ __forceinline__ float bf2f(unsigned short h){
  unsigned u = ((unsigned)h) << 16;
  return __builtin_bit_cast(float, u);
}
__device__ __forceinline__ f32x4 mfma16(bf16x8 a, bf16x8 b, f32x4 c){
  return __builtin_amdgcn_mfma_f32_16x16x32_bf16(a, b, c, 0, 0, 0);
}

// ---------------- prep: split x into bf16 hi/lo ----------------
__global__ void prep_x_kernel(const float* __restrict__ x,
                              unsigned short* __restrict__ xh,
                              unsigned short* __restrict__ xl){
  const int n4 = MROWS*DM/4;
  for (int i = blockIdx.x*blockDim.x + threadIdx.x; i < n4; i += gridDim.x*blockDim.x){
    float4 v = reinterpret_cast<const float4*>(x)[i];
    float f[4] = {v.x, v.y, v.z, v.w};
    us4 h, lo;
    #pragma unroll
    for (int j = 0; j < 4; ++j){
      unsigned short hh = f2bf(f[j]);
      h[j]  = hh;
      lo[j] = f2bf(f[j] - bf2f(hh));
    }
    reinterpret_cast<us4*>(xh)[i] = h;
    reinterpret_cast<us4*>(xl)[i] = lo;
  }
}

// ---------------- prep: weights + bias ----------------
__global__ void prep_w_kernel(const float* __restrict__ wq, const float* __restrict__ wk,
                              const float* __restrict__ wv,
                              const float* __restrict__ bq, const float* __restrict__ bk,
                              const float* __restrict__ bv,
                              unsigned short* __restrict__ Whi, unsigned short* __restrict__ Wlo,
                              float* __restrict__ bias_all){
  const int n = NALL*DM;
  for (int i = blockIdx.x*blockDim.x + threadIdx.x; i < n; i += gridDim.x*blockDim.x){
    const int r = i >> 10, c = i & 1023;
    float v;
    if (r < 64)       v = wq[r*1024 + c];
    else if (r < 128) v = wk[(r-64)*1024 + c];
    else              v = wv[(r-128)*1024 + c];
    const unsigned short h = f2bf(v);
    Whi[i] = h;
    if (r < 128) Wlo[i] = f2bf(v - bf2f(h));
    if (i < NALL) bias_all[i] = (i < 64) ? bq[i] : (i < 128) ? bk[i-64] : bv[i-128];
  }
}

// ---------------- QKV GEMM (unchanged from passing round) ----------------
__global__ __launch_bounds__(256) void qkv_gemm_kernel(
    const unsigned short* __restrict__ xh, const unsigned short* __restrict__ xl,
    const unsigned short* __restrict__ Whi, const unsigned short* __restrict__ Wlo,
    const float* __restrict__ bias_all,
    unsigned short* __restrict__ Qh, unsigned short* __restrict__ Ql,
    unsigned short* __restrict__ Kh, unsigned short* __restrict__ Kl,
    unsigned short* __restrict__ Vt)
{
  __shared__ unsigned short tA[128*32];
  __shared__ unsigned short tB[128*32];
  const int bx = blockIdx.x;
  const int mtile = bx & 63;
  const int ntile = bx >> 6;              // 0..8
  const int m0 = mtile*128, n0 = ntile*128;
  const int tid = threadIdx.x;
  const int l = tid & 63, w = tid >> 6;
  const int lr = l >> 4, lc = l & 15;
  const int wr = w >> 1, wc = w & 1;

  f32x4 acc[4][4] = {};

  const int npass = (ntile == 0) ? 3 : 1;
  for (int pass = 0; pass < npass; ++pass){
    const unsigned short* Ab = (pass == 2) ? xl : xh;
    const unsigned short* Bb = (pass == 1) ? Wlo : (Whi + (size_t)n0*DM);
    for (int k0 = 0; k0 < DM; k0 += 32){
      __syncthreads();
      #pragma unroll
      for (int p = 0; p < 2; ++p){
        const int c   = tid + p*256;
        const int row = c >> 2, kq = c & 3;
        const unsigned short* ga = Ab + ((size_t)(m0+row)*DM + k0 + kq*8);
        const unsigned short* gb = Bb + ((size_t)row*DM     + k0 + kq*8);
        const int lbase = w*1024 + p*4096;
        __builtin_amdgcn_global_load_lds(
            (const __attribute__((address_space(1))) void*)ga,
            (__attribute__((address_space(3))) void*)((char*)tA + lbase), 16, 0, 0);
        __builtin_amdgcn_global_load_lds(
            (const __attribute__((address_space(1))) void*)gb,
            (__attribute__((address_space(3))) void*)((char*)tB + lbase), 16, 0, 0);
      }
      __syncthreads();
      bf16x8 af[4], bfr[4];
      #pragma unroll
      for (int mi = 0; mi < 4; ++mi){
        const int r = wr*64 + mi*16 + lc;
        af[mi] = *reinterpret_cast<const bf16x8*>((const char*)tA + r*64 + lr*16);
      }
      #pragma unroll
      for (int ni = 0; ni < 4; ++ni){
        const int r = wc*64 + ni*16 + lc;
        bfr[ni] = *reinterpret_cast<const bf16x8*>((const char*)tB + r*64 + lr*16);
      }
      #pragma unroll
      for (int mi = 0; mi < 4; ++mi)
        #pragma unroll
        for (int ni = 0; ni < 4; ++ni)
          acc[mi][ni] = mfma16(af[mi], bfr[ni], acc[mi][ni]);
    }
  }

  #pragma unroll
  for (int ni = 0; ni < 4; ++ni){
    const int col = n0 + wc*64 + ni*16 + lc;
    const float bias = bias_all[col];
    #pragma unroll
    for (int mi = 0; mi < 4; ++mi){
      const int rowb = m0 + wr*64 + mi*16 + lr*4;
      if (ntile > 0){
        const int vc = col - 128;
        const int b  = rowb >> 11;
        const int s  = rowb & 2047;
        us4 pk;
        #pragma unroll
        for (int i = 0; i < 4; ++i) pk[i] = f2bf(acc[mi][ni][i] + bias);
        *reinterpret_cast<us4*>(&Vt[((size_t)b*DM + vc)*SS + s]) = pk;
      } else {
        #pragma unroll
        for (int i = 0; i < 4; ++i){
          const int row = rowb + i;
          const float v = acc[mi][ni][i] + bias;
          const unsigned short h   = f2bf(v);
          const unsigned short lo2 = f2bf(v - bf2f(h));
          if (col < DH){
            Qh[(size_t)row*DH + col] = h;
            Ql[(size_t)row*DH + col] = lo2;
          } else {
            Kh[(size_t)row*DH + col - DH] = h;
            Kl[(size_t)row*DH + col - DH] = lo2;
          }
        }
      }
    }
  }
}

// ---------------- diag: per-row softmax anchor M_r = q_r.k_r + 20, zero lpart ----------------
__global__ __launch_bounds__(256) void diag_kernel(
    const unsigned short* __restrict__ Qh, const unsigned short* __restrict__ Ql,
    const unsigned short* __restrict__ Kh, const unsigned short* __restrict__ Kl,
    float* __restrict__ Mrow, float* __restrict__ lpart)
{
  const int r = blockIdx.x*256 + threadIdx.x;   // 0..8191
  float dot = 0.f;
  #pragma unroll
  for (int c = 0; c < 8; ++c){
    bf16x8 a  = *reinterpret_cast<const bf16x8*>(Qh + (size_t)r*DH + c*8);
    bf16x8 al = *reinterpret_cast<const bf16x8*>(Ql + (size_t)r*DH + c*8);
    bf16x8 bh = *reinterpret_cast<const bf16x8*>(Kh + (size_t)r*DH + c*8);
    bf16x8 bl = *reinterpret_cast<const bf16x8*>(Kl + (size_t)r*DH + c*8);
    #pragma unroll
    for (int j = 0; j < 8; ++j)
      dot += (bf2f((unsigned short)a[j]) + bf2f((unsigned short)al[j])) *
             (bf2f((unsigned short)bh[j]) + bf2f((unsigned short)bl[j]));
  }
  Mrow[r] = dot + 20.0f;
  #pragma unroll
  for (int kc = 0; kc < 8; ++kc) lpart[(size_t)r*8 + kc] = 0.f;
}

// ---------------- scores: P = exp(S - M_r) bf16, per-chunk row sums ----------------
// grid.x = 288 flat (qt,kc) valid pairs, grid.y = batch. 8 waves x 32 keys = 256-key chunk.
__global__ __launch_bounds__(512) void scores_kernel(
    const unsigned short* __restrict__ Qh, const unsigned short* __restrict__ Ql,
    const unsigned short* __restrict__ Kh, const unsigned short* __restrict__ Kl,
    const float* __restrict__ Mrow,
    unsigned short* __restrict__ Pbuf, float* __restrict__ lpart)
{
  __shared__ float ws_s[8][32];
  const int t = blockIdx.x, b = blockIdx.y;
  int g = 0;
  while (g < 7 && 4*(g+1)*(g+2) <= t) ++g;
  const int base = 4*g*(g+1);
  const int qt = 8*g + (t - base)/(g+1);
  const int kc = (t - base)%(g+1);
  const int q0 = qt*32, kbase = kc*256;
  const int tid = threadIdx.x, l = tid & 63, w = tid >> 6;
  const int lr = l >> 4, lc = l & 15;
  const int kw0 = kbase + w*32;
  const float L2E = 1.4426950408889634f;

  bf16x8 qh[2][2], qlo[2][2], kh[2][2], kl2[2][2];
  #pragma unroll
  for (int qi = 0; qi < 2; ++qi)
    #pragma unroll
    for (int ks = 0; ks < 2; ++ks){
      const size_t off = (size_t)(b*SS + q0 + qi*16 + lc)*DH + ks*32 + lr*8;
      qh[qi][ks]  = *reinterpret_cast<const bf16x8*>(&Qh[off]);
      qlo[qi][ks] = *reinterpret_cast<const bf16x8*>(&Ql[off]);
    }
  #pragma unroll
  for (int ki = 0; ki < 2; ++ki)
    #pragma unroll
    for (int ks = 0; ks < 2; ++ks){
      const size_t off = (size_t)(b*SS + kw0 + ki*16 + lc)*DH + ks*32 + lr*8;
      kh[ki][ks]  = *reinterpret_cast<const bf16x8*>(&Kh[off]);
      kl2[ki][ks] = *reinterpret_cast<const bf16x8*>(&Kl[off]);
    }

  f32x4 sa[2][2] = {};
  #pragma unroll
  for (int qi = 0; qi < 2; ++qi)
    #pragma unroll
    for (int ki = 0; ki < 2; ++ki)
      #pragma unroll
      for (int ks = 0; ks < 2; ++ks){
        sa[qi][ki] = mfma16(qh[qi][ks],  kh[ki][ks],  sa[qi][ki]);
        sa[qi][ki] = mfma16(qh[qi][ks],  kl2[ki][ks], sa[qi][ki]);
        sa[qi][ki] = mfma16(qlo[qi][ks], kh[ki][ks],  sa[qi][ki]);
      }

  float Mv[2][4];
  #pragma unroll
  for (int qi = 0; qi < 2; ++qi)
    #pragma unroll
    for (int i = 0; i < 4; ++i)
      Mv[qi][i] = Mrow[b*SS + q0 + qi*16 + lr*4 + i];

  const bool diagblk = (kc == (qt >> 3));
  float psum[2][4] = {};
  #pragma unroll
  for (int qi = 0; qi < 2; ++qi)
    #pragma unroll
    for (int ki = 0; ki < 2; ++ki)
      #pragma unroll
      for (int i = 0; i < 4; ++i){
        const int qrow = qi*16 + lr*4 + i;
        const int kcol = w*32 + ki*16 + lc;
        float p;
        if (diagblk && (kbase + kcol > q0 + qrow)) p = 0.f;
        else p = exp2f((sa[qi][ki][i] - Mv[qi][i])*L2E);
        Pbuf[(size_t)(b*SS + q0 + qrow)*SS + kbase + kcol] = f2bf(p);
        psum[qi][i] += p;
      }

  // reduce row sums over the 16 lanes of each lr-group
  #pragma unroll
  for (int qi = 0; qi < 2; ++qi)
    #pragma unroll
    for (int i = 0; i < 4; ++i){
      float s = psum[qi][i];
      #pragma unroll
      for (int m = 1; m < 16; m <<= 1) s += __shfl_xor(s, m);
      psum[qi][i] = s;
    }
  if (lc == 0){
    #pragma unroll
    for (int qi = 0; qi < 2; ++qi)
      #pragma unroll
      for (int i = 0; i < 4; ++i)
        ws_s[w][qi*16 + lr*4 + i] = psum[qi][i];
  }
  __syncthreads();
  if (tid < 32){
    float s = 0.f;
    #pragma unroll
    for (int w2 = 0; w2 < 8; ++w2) s += ws_s[w2][tid];
    lpart[(size_t)(b*SS + q0 + tid)*8 + kc] = s;
  }
}

// ---------------- combine: l_r = sum of chunk partials ----------------
__global__ __launch_bounds__(256) void combine_kernel(const float* __restrict__ lpart,
                                                      float* __restrict__ lfin){
  const int r = blockIdx.x*256 + threadIdx.x;
  float s = 0.f;
  #pragma unroll
  for (int kc = 0; kc < 8; ++kc) s += lpart[(size_t)r*8 + kc];
  lfin[r] = s;
}

// ---------------- PV: out = (P @ V) / l  — pure GEMM, no LDS, no barriers ----------------
// 512 blocks: 32 qc-tiles (64 rows) x 4 batch x 4 col-chunks (256 cols).
// XCD decode: v&7 = XCD; each XCD owns 2 (b,cc) V-slices for L2 locality.
__global__ __launch_bounds__(512) void pv_kernel(
    const unsigned short* __restrict__ Pbuf, const unsigned short* __restrict__ Vt,
    const float* __restrict__ lfin, float* __restrict__ out)
{
  const int v = blockIdx.x;
  const int xcd = v & 7, tt = v >> 3;        // tt 0..63
  const int sl = xcd*2 + (tt >> 5);          // slice 0..15 = (b,cc)
  const int j = tt & 31;
  const int qc = (tt < 32) ? j : (31 - j);   // round1 ascending, round2 descending
  const int b = sl >> 2, cc = sl & 3;
  const int q0B = qc*64;
  const int tid = threadIdx.x, l = tid & 63, w = tid >> 6;
  const int lr = l >> 4, lc = l & 15;
  const int wr = w >> 2, wc = w & 3;         // 2x4 wave grid: 32 rows x 64 cols each

  f32x4 o[2][4] = {};
  const int nkb = qc/4 + 1;
  for (int kb = 0; kb < nkb; ++kb){
    const int kbase = kb*256;
    #pragma unroll
    for (int ks2 = 0; ks2 < 8; ++ks2){
      const int koff = kbase + ks2*32 + lr*8;
      bf16x8 pa[2], vb[4];
      #pragma unroll
      for (int qi = 0; qi < 2; ++qi)
        pa[qi] = *reinterpret_cast<const bf16x8*>(
            &Pbuf[(size_t)(b*SS + q0B + wr*32 + qi*16 + lc)*SS + koff]);
      #pragma unroll
      for (int ci = 0; ci < 4; ++ci)
        vb[ci] = *reinterpret_cast<const bf16x8*>(
            &Vt[((size_t)b*DM + cc*256 + wc*64 + ci*16 + lc)*SS + koff]);
      #pragma unroll
      for (int qi = 0; qi < 2; ++qi)
        #pragma unroll
        for (int ci = 0; ci < 4; ++ci)
          o[qi][ci] = mfma16(pa[qi], vb[ci], o[qi][ci]);
    }
  }

  #pragma unroll
  for (int qi = 0; qi < 2; ++qi)
    #pragma unroll
    for (int i = 0; i < 4; ++i){
      const int row = q0B + wr*32 + qi*16 + lr*4 + i;
      const float linv = 1.0f / lfin[b*SS + row];
      #pragma unroll
      for (int ci = 0; ci < 4; ++ci)
        out[(size_t)(b*SS + row)*DM + cc*256 + wc*64 + ci*16 + lc] = o[qi][ci][i]*linv;
    }
}

// ---------------- launcher ----------------
extern "C" void kernel_launch(void* const* d_in, const int* in_sizes, int n_in,
                              void* d_out, int out_size, void* d_ws, size_t ws_size,
                              hipStream_t stream)
{
  const float* x  = (const float*)d_in[0];
  const float* wq = (const float*)d_in[1];
  const float* bq = (const float*)d_in[2];
  const float* wk = (const float*)d_in[3];
  const float* bk = (const float*)d_in[4];
  const float* wv = (const float*)d_in[5];
  const float* bv = (const float*)d_in[6];
  float* out = (float*)d_out;

  char* ws = (char*)d_ws;
  // Pbuf aliases xh/xl: xh/xl are consumed by qkv_gemm and rewritten by prep_x
  // at the start of every call, so scores may overwrite them afterwards.
  unsigned short* xh  = (unsigned short*)(ws + 0);          // 16,777,216
  unsigned short* xl  = (unsigned short*)(ws + 16777216);   // 16,777,216
  unsigned short* Pbuf= (unsigned short*)(ws + 0);          // 33,554,432 (alias)
  unsigned short* Whi = (unsigned short*)(ws + 33554432);   //  2,359,296
  unsigned short* Wlo = (unsigned short*)(ws + 35913728);   //    262,144
  float* bias_all     = (float*)(ws + 36175872);            //      4,608
  unsigned short* Qh  = (unsigned short*)(ws + 36180480);   //  1,048,576
  unsigned short* Ql  = (unsigned short*)(ws + 37229056);   //  1,048,576
  unsigned short* Kh  = (unsigned short*)(ws + 38277632);   //  1,048,576
  unsigned short* Kl  = (unsigned short*)(ws + 39326208);   //  1,048,576
  unsigned short* Vt  = (unsigned short*)(ws + 40374784);   // 16,777,216
  float* Mrow         = (float*)(ws + 57152000);            //     32,768
  float* lpart        = (float*)(ws + 57184768);            //    262,144
  float* lfin         = (float*)(ws + 57446912);            //     32,768
  // total: 57,479,680 bytes

  hipLaunchKernelGGL(prep_x_kernel, dim3(2048), dim3(256), 0, stream, x, xh, xl);
  hipLaunchKernelGGL(prep_w_kernel, dim3(1184), dim3(256), 0, stream,
                     wq, wk, wv, bq, bk, bv, Whi, Wlo, bias_all);
  hipLaunchKernelGGL(qkv_gemm_kernel, dim3(576), dim3(256), 0, stream,
                     xh, xl, Whi, Wlo, bias_all, Qh, Ql, Kh, Kl, Vt);
  hipLaunchKernelGGL(diag_kernel, dim3(32), dim3(256), 0, stream,
                     Qh, Ql, Kh, Kl, Mrow, lpart);
  hipLaunchKernelGGL(scores_kernel, dim3(288, 4), dim3(512), 0, stream,
                     Qh, Ql, Kh, Kl, Mrow, Pbuf, lpart);
  hipLaunchKernelGGL(combine_kernel, dim3(32), dim3(256), 0, stream, lpart, lfin);
  hipLaunchKernelGGL(pv_kernel, dim3(512), dim3(512), 0, stream, Pbuf, Vt, lfin, out);
}

// Round 3
// 166.865 us; speedup vs baseline: 1.4202x; 1.2805x over previous
//
#include <hip/hip_runtime.h>
#include <cstdint>
#include <cstddef>

// Problem constants
#define NB 4
#define SS 2048
#define DM 1024
#define DH 64
#define MROWS (NB*SS)      // 8192
#define NALL  (2*DH + DM)  // 1152

typedef __attribute__((ext_vector_type(8))) short bf16x8;
typedef __attribute__((ext_vector_type(4))) float f32x4;
typedef __attribute__((ext_vector_type(4))) unsigned short us4;

__device__ __forceinline__ unsigned short f2bf(float f){
  unsigned u = __builtin_bit_cast(unsigned, f);
  u = (u + 0x7fffu + ((u >> 16) & 1u)) >> 16;   // RNE
  return (unsigned short)u;
}
__device__ __forceinline__ float bf2f(unsigned short h){
  unsigned u = ((unsigned)h) << 16;
  return __builtin_bit_cast(float, u);
}
__device__ __forceinline__ f32x4 mfma16(bf16x8 a, bf16x8 b, f32x4 c){
  return __builtin_amdgcn_mfma_f32_16x16x32_bf16(a, b, c, 0, 0, 0);
}

// ---------------- prep: split x into bf16 hi/lo ----------------
__global__ void prep_x_kernel(const float* __restrict__ x,
                              unsigned short* __restrict__ xh,
                              unsigned short* __restrict__ xl){
  const int n4 = MROWS*DM/4;
  for (int i = blockIdx.x*blockDim.x + threadIdx.x; i < n4; i += gridDim.x*blockDim.x){
    float4 v = reinterpret_cast<const float4*>(x)[i];
    float f[4] = {v.x, v.y, v.z, v.w};
    us4 h, lo;
    #pragma unroll
    for (int j = 0; j < 4; ++j){
      unsigned short hh = f2bf(f[j]);
      h[j]  = hh;
      lo[j] = f2bf(f[j] - bf2f(hh));
    }
    reinterpret_cast<us4*>(xh)[i] = h;
    reinterpret_cast<us4*>(xl)[i] = lo;
  }
}

// ---------------- prep: weights + bias ----------------
__global__ void prep_w_kernel(const float* __restrict__ wq, const float* __restrict__ wk,
                              const float* __restrict__ wv,
                              const float* __restrict__ bq, const float* __restrict__ bk,
                              const float* __restrict__ bv,
                              unsigned short* __restrict__ Whi, unsigned short* __restrict__ Wlo,
                              float* __restrict__ bias_all){
  const int n = NALL*DM;
  for (int i = blockIdx.x*blockDim.x + threadIdx.x; i < n; i += gridDim.x*blockDim.x){
    const int r = i >> 10, c = i & 1023;
    float v;
    if (r < 64)       v = wq[r*1024 + c];
    else if (r < 128) v = wk[(r-64)*1024 + c];
    else              v = wv[(r-128)*1024 + c];
    const unsigned short h = f2bf(v);
    Whi[i] = h;
    if (r < 128) Wlo[i] = f2bf(v - bf2f(h));
    if (i < NALL) bias_all[i] = (i < 64) ? bq[i] : (i < 128) ? bk[i-64] : bv[i-128];
  }
}

// ---------------- QKV GEMM (unchanged) ----------------
__global__ __launch_bounds__(256) void qkv_gemm_kernel(
    const unsigned short* __restrict__ xh, const unsigned short* __restrict__ xl,
    const unsigned short* __restrict__ Whi, const unsigned short* __restrict__ Wlo,
    const float* __restrict__ bias_all,
    unsigned short* __restrict__ Qh, unsigned short* __restrict__ Ql,
    unsigned short* __restrict__ Kh, unsigned short* __restrict__ Kl,
    unsigned short* __restrict__ Vt)
{
  __shared__ unsigned short tA[128*32];
  __shared__ unsigned short tB[128*32];
  const int bx = blockIdx.x;
  const int mtile = bx & 63;
  const int ntile = bx >> 6;              // 0..8
  const int m0 = mtile*128, n0 = ntile*128;
  const int tid = threadIdx.x;
  const int l = tid & 63, w = tid >> 6;
  const int lr = l >> 4, lc = l & 15;
  const int wr = w >> 1, wc = w & 1;

  f32x4 acc[4][4] = {};

  const int npass = (ntile == 0) ? 3 : 1;
  for (int pass = 0; pass < npass; ++pass){
    const unsigned short* Ab = (pass == 2) ? xl : xh;
    const unsigned short* Bb = (pass == 1) ? Wlo : (Whi + (size_t)n0*DM);
    for (int k0 = 0; k0 < DM; k0 += 32){
      __syncthreads();
      #pragma unroll
      for (int p = 0; p < 2; ++p){
        const int c   = tid + p*256;
        const int row = c >> 2, kq = c & 3;
        const unsigned short* ga = Ab + ((size_t)(m0+row)*DM + k0 + kq*8);
        const unsigned short* gb = Bb + ((size_t)row*DM     + k0 + kq*8);
        const int lbase = w*1024 + p*4096;
        __builtin_amdgcn_global_load_lds(
            (const __attribute__((address_space(1))) void*)ga,
            (__attribute__((address_space(3))) void*)((char*)tA + lbase), 16, 0, 0);
        __builtin_amdgcn_global_load_lds(
            (const __attribute__((address_space(1))) void*)gb,
            (__attribute__((address_space(3))) void*)((char*)tB + lbase), 16, 0, 0);
      }
      __syncthreads();
      bf16x8 af[4], bfr[4];
      #pragma unroll
      for (int mi = 0; mi < 4; ++mi){
        const int r = wr*64 + mi*16 + lc;
        af[mi] = *reinterpret_cast<const bf16x8*>((const char*)tA + r*64 + lr*16);
      }
      #pragma unroll
      for (int ni = 0; ni < 4; ++ni){
        const int r = wc*64 + ni*16 + lc;
        bfr[ni] = *reinterpret_cast<const bf16x8*>((const char*)tB + r*64 + lr*16);
      }
      #pragma unroll
      for (int mi = 0; mi < 4; ++mi)
        #pragma unroll
        for (int ni = 0; ni < 4; ++ni)
          acc[mi][ni] = mfma16(af[mi], bfr[ni], acc[mi][ni]);
    }
  }

  #pragma unroll
  for (int ni = 0; ni < 4; ++ni){
    const int col = n0 + wc*64 + ni*16 + lc;
    const float bias = bias_all[col];
    #pragma unroll
    for (int mi = 0; mi < 4; ++mi){
      const int rowb = m0 + wr*64 + mi*16 + lr*4;
      if (ntile > 0){
        const int vc = col - 128;
        const int b  = rowb >> 11;
        const int s  = rowb & 2047;
        us4 pk;
        #pragma unroll
        for (int i = 0; i < 4; ++i) pk[i] = f2bf(acc[mi][ni][i] + bias);
        *reinterpret_cast<us4*>(&Vt[((size_t)b*DM + vc)*SS + s]) = pk;
      } else {
        #pragma unroll
        for (int i = 0; i < 4; ++i){
          const int row = rowb + i;
          const float v = acc[mi][ni][i] + bias;
          const unsigned short h   = f2bf(v);
          const unsigned short lo2 = f2bf(v - bf2f(h));
          if (col < DH){
            Qh[(size_t)row*DH + col] = h;
            Ql[(size_t)row*DH + col] = lo2;
          } else {
            Kh[(size_t)row*DH + col - DH] = h;
            Kl[(size_t)row*DH + col - DH] = lo2;
          }
        }
      }
    }
  }
}

// ---------------- diag: per-row softmax anchor M_r = q_r.k_r + 20, zero lpart ----------------
__global__ __launch_bounds__(256) void diag_kernel(
    const unsigned short* __restrict__ Qh, const unsigned short* __restrict__ Ql,
    const unsigned short* __restrict__ Kh, const unsigned short* __restrict__ Kl,
    float* __restrict__ Mrow, float* __restrict__ lpart)
{
  const int r = blockIdx.x*256 + threadIdx.x;   // 0..8191
  float dot = 0.f;
  #pragma unroll
  for (int c = 0; c < 8; ++c){
    bf16x8 a  = *reinterpret_cast<const bf16x8*>(Qh + (size_t)r*DH + c*8);
    bf16x8 al = *reinterpret_cast<const bf16x8*>(Ql + (size_t)r*DH + c*8);
    bf16x8 bh = *reinterpret_cast<const bf16x8*>(Kh + (size_t)r*DH + c*8);
    bf16x8 bl = *reinterpret_cast<const bf16x8*>(Kl + (size_t)r*DH + c*8);
    #pragma unroll
    for (int j = 0; j < 8; ++j)
      dot += (bf2f((unsigned short)a[j]) + bf2f((unsigned short)al[j])) *
             (bf2f((unsigned short)bh[j]) + bf2f((unsigned short)bl[j]));
  }
  Mrow[r] = dot + 20.0f;
  #pragma unroll
  for (int kc = 0; kc < 8; ++kc) lpart[(size_t)r*8 + kc] = 0.f;
}

// ---------------- scores: P = exp(S - M_r) bf16, per-chunk row sums ----------------
__global__ __launch_bounds__(512) void scores_kernel(
    const unsigned short* __restrict__ Qh, const unsigned short* __restrict__ Ql,
    const unsigned short* __restrict__ Kh, const unsigned short* __restrict__ Kl,
    const float* __restrict__ Mrow,
    unsigned short* __restrict__ Pbuf, float* __restrict__ lpart)
{
  __shared__ float ws_s[8][32];
  const int t = blockIdx.x, b = blockIdx.y;
  int g = 0;
  while (g < 7 && 4*(g+1)*(g+2) <= t) ++g;
  const int base = 4*g*(g+1);
  const int qt = 8*g + (t - base)/(g+1);
  const int kc = (t - base)%(g+1);
  const int q0 = qt*32, kbase = kc*256;
  const int tid = threadIdx.x, l = tid & 63, w = tid >> 6;
  const int lr = l >> 4, lc = l & 15;
  const int kw0 = kbase + w*32;
  const float L2E = 1.4426950408889634f;

  bf16x8 qh[2][2], qlo[2][2], kh[2][2], kl2[2][2];
  #pragma unroll
  for (int qi = 0; qi < 2; ++qi)
    #pragma unroll
    for (int ks = 0; ks < 2; ++ks){
      const size_t off = (size_t)(b*SS + q0 + qi*16 + lc)*DH + ks*32 + lr*8;
      qh[qi][ks]  = *reinterpret_cast<const bf16x8*>(&Qh[off]);
      qlo[qi][ks] = *reinterpret_cast<const bf16x8*>(&Ql[off]);
    }
  #pragma unroll
  for (int ki = 0; ki < 2; ++ki)
    #pragma unroll
    for (int ks = 0; ks < 2; ++ks){
      const size_t off = (size_t)(b*SS + kw0 + ki*16 + lc)*DH + ks*32 + lr*8;
      kh[ki][ks]  = *reinterpret_cast<const bf16x8*>(&Kh[off]);
      kl2[ki][ks] = *reinterpret_cast<const bf16x8*>(&Kl[off]);
    }

  f32x4 sa[2][2] = {};
  #pragma unroll
  for (int qi = 0; qi < 2; ++qi)
    #pragma unroll
    for (int ki = 0; ki < 2; ++ki)
      #pragma unroll
      for (int ks = 0; ks < 2; ++ks){
        sa[qi][ki] = mfma16(qh[qi][ks],  kh[ki][ks],  sa[qi][ki]);
        sa[qi][ki] = mfma16(qh[qi][ks],  kl2[ki][ks], sa[qi][ki]);
        sa[qi][ki] = mfma16(qlo[qi][ks], kh[ki][ks],  sa[qi][ki]);
      }

  float Mv[2][4];
  #pragma unroll
  for (int qi = 0; qi < 2; ++qi)
    #pragma unroll
    for (int i = 0; i < 4; ++i)
      Mv[qi][i] = Mrow[b*SS + q0 + qi*16 + lr*4 + i];

  const bool diagblk = (kc == (qt >> 3));
  float psum[2][4] = {};
  #pragma unroll
  for (int qi = 0; qi < 2; ++qi)
    #pragma unroll
    for (int ki = 0; ki < 2; ++ki)
      #pragma unroll
      for (int i = 0; i < 4; ++i){
        const int qrow = qi*16 + lr*4 + i;
        const int kcol = w*32 + ki*16 + lc;
        float p;
        if (diagblk && (kbase + kcol > q0 + qrow)) p = 0.f;
        else p = exp2f((sa[qi][ki][i] - Mv[qi][i])*L2E);
        Pbuf[(size_t)(b*SS + q0 + qrow)*SS + kbase + kcol] = f2bf(p);
        psum[qi][i] += p;
      }

  #pragma unroll
  for (int qi = 0; qi < 2; ++qi)
    #pragma unroll
    for (int i = 0; i < 4; ++i){
      float s = psum[qi][i];
      #pragma unroll
      for (int m = 1; m < 16; m <<= 1) s += __shfl_xor(s, m);
      psum[qi][i] = s;
    }
  if (lc == 0){
    #pragma unroll
    for (int qi = 0; qi < 2; ++qi)
      #pragma unroll
      for (int i = 0; i < 4; ++i)
        ws_s[w][qi*16 + lr*4 + i] = psum[qi][i];
  }
  __syncthreads();
  if (tid < 32){
    float s = 0.f;
    #pragma unroll
    for (int w2 = 0; w2 < 8; ++w2) s += ws_s[w2][tid];
    lpart[(size_t)(b*SS + q0 + tid)*8 + kc] = s;
  }
}

// ---------------- combine: l_r = sum of chunk partials ----------------
__global__ __launch_bounds__(256) void combine_kernel(const float* __restrict__ lpart,
                                                      float* __restrict__ lfin){
  const int r = blockIdx.x*256 + threadIdx.x;
  float s = 0.f;
  #pragma unroll
  for (int kc = 0; kc < 8; ++kc) s += lpart[(size_t)r*8 + kc];
  lfin[r] = s;
}

// ---------------- PV GEMM (m97 structure): out = (P @ V) / l ----------------
// 128x128 tile, BK=32, 4 waves (2x2), global_load_lds width 16.
// Grid 512 = 16 mt x 8 nt x 4 b, heavy-mt-first for load balance.
// K extent per mtile = (mt/2+1)*256 — exactly the end of every row's diagonal
// 256-chunk, whose masked region scores_kernel zero-fills (garbage-safe).
__global__ __launch_bounds__(256) void pv_kernel(
    const unsigned short* __restrict__ Pbuf, const unsigned short* __restrict__ Vt,
    const float* __restrict__ lfin, float* __restrict__ out)
{
  __shared__ unsigned short tA[128*32];
  __shared__ unsigned short tB[128*32];
  const int bx = blockIdx.x;           // 0..511
  const int nt = bx & 7;
  const int t2 = bx >> 3;              // 0..63
  const int b  = t2 & 3;
  const int mt = 15 - (t2 >> 2);       // heavy (large-K) tiles first
  const int m0 = mt*128, n0 = nt*128;
  const int tid = threadIdx.x;
  const int l = tid & 63, w = tid >> 6;
  const int lr = l >> 4, lc = l & 15;
  const int wr = w >> 1, wc = w & 1;

  const unsigned short* Ab = Pbuf + (size_t)(b*SS + m0)*SS;
  const unsigned short* Bb = Vt   + (size_t)(b*DM + n0)*SS;

  f32x4 acc[4][4] = {};
  const int kend = (mt/2 + 1)*256;
  for (int k0 = 0; k0 < kend; k0 += 32){
    __syncthreads();
    #pragma unroll
    for (int p = 0; p < 2; ++p){
      const int c   = tid + p*256;        // 512 x 16B chunks per tile
      const int row = c >> 2, kq = c & 3;
      const unsigned short* ga = Ab + ((size_t)row*SS + k0 + kq*8);
      const unsigned short* gb = Bb + ((size_t)row*SS + k0 + kq*8);
      const int lbase = w*1024 + p*4096;
      __builtin_amdgcn_global_load_lds(
          (const __attribute__((address_space(1))) void*)ga,
          (__attribute__((address_space(3))) void*)((char*)tA + lbase), 16, 0, 0);
      __builtin_amdgcn_global_load_lds(
          (const __attribute__((address_space(1))) void*)gb,
          (__attribute__((address_space(3))) void*)((char*)tB + lbase), 16, 0, 0);
    }
    __syncthreads();
    bf16x8 af[4], bfr[4];
    #pragma unroll
    for (int mi = 0; mi < 4; ++mi){
      const int r = wr*64 + mi*16 + lc;
      af[mi] = *reinterpret_cast<const bf16x8*>((const char*)tA + r*64 + lr*16);
    }
    #pragma unroll
    for (int ni = 0; ni < 4; ++ni){
      const int r = wc*64 + ni*16 + lc;
      bfr[ni] = *reinterpret_cast<const bf16x8*>((const char*)tB + r*64 + lr*16);
    }
    #pragma unroll
    for (int mi = 0; mi < 4; ++mi)
      #pragma unroll
      for (int ni = 0; ni < 4; ++ni)
        acc[mi][ni] = mfma16(af[mi], bfr[ni], acc[mi][ni]);
  }

  #pragma unroll
  for (int mi = 0; mi < 4; ++mi){
    #pragma unroll
    for (int i = 0; i < 4; ++i){
      const int row = m0 + wr*64 + mi*16 + lr*4 + i;
      const float linv = 1.0f / lfin[b*SS + row];
      #pragma unroll
      for (int ni = 0; ni < 4; ++ni){
        const int col = n0 + wc*64 + ni*16 + lc;
        out[(size_t)(b*SS + row)*DM + col] = acc[mi][ni][i]*linv;
      }
    }
  }
}

// ---------------- launcher ----------------
extern "C" void kernel_launch(void* const* d_in, const int* in_sizes, int n_in,
                              void* d_out, int out_size, void* d_ws, size_t ws_size,
                              hipStream_t stream)
{
  const float* x  = (const float*)d_in[0];
  const float* wq = (const float*)d_in[1];
  const float* bq = (const float*)d_in[2];
  const float* wk = (const float*)d_in[3];
  const float* bk = (const float*)d_in[4];
  const float* wv = (const float*)d_in[5];
  const float* bv = (const float*)d_in[6];
  float* out = (float*)d_out;

  char* ws = (char*)d_ws;
  // Pbuf aliases xh/xl: xh/xl are consumed by qkv_gemm and rewritten by prep_x
  // at the start of every call, so scores may overwrite them afterwards.
  unsigned short* xh  = (unsigned short*)(ws + 0);          // 16,777,216
  unsigned short* xl  = (unsigned short*)(ws + 16777216);   // 16,777,216
  unsigned short* Pbuf= (unsigned short*)(ws + 0);          // 33,554,432 (alias)
  unsigned short* Whi = (unsigned short*)(ws + 33554432);   //  2,359,296
  unsigned short* Wlo = (unsigned short*)(ws + 35913728);   //    262,144
  float* bias_all     = (float*)(ws + 36175872);            //      4,608
  unsigned short* Qh  = (unsigned short*)(ws + 36180480);   //  1,048,576
  unsigned short* Ql  = (unsigned short*)(ws + 37229056);   //  1,048,576
  unsigned short* Kh  = (unsigned short*)(ws + 38277632);   //  1,048,576
  unsigned short* Kl  = (unsigned short*)(ws + 39326208);   //  1,048,576
  unsigned short* Vt  = (unsigned short*)(ws + 40374784);   // 16,777,216
  float* Mrow         = (float*)(ws + 57152000);            //     32,768
  float* lpart        = (float*)(ws + 57184768);            //    262,144
  float* lfin         = (float*)(ws + 57446912);            //     32,768
  // total: 57,479,680 bytes

  hipLaunchKernelGGL(prep_x_kernel, dim3(2048), dim3(256), 0, stream, x, xh, xl);
  hipLaunchKernelGGL(prep_w_kernel, dim3(1184), dim3(256), 0, stream,
                     wq, wk, wv, bq, bk, bv, Whi, Wlo, bias_all);
  hipLaunchKernelGGL(qkv_gemm_kernel, dim3(576), dim3(256), 0, stream,
                     xh, xl, Whi, Wlo, bias_all, Qh, Ql, Kh, Kl, Vt);
  hipLaunchKernelGGL(diag_kernel, dim3(32), dim3(256), 0, stream,
                     Qh, Ql, Kh, Kl, Mrow, lpart);
  hipLaunchKernelGGL(scores_kernel, dim3(288, 4), dim3(512), 0, stream,
                     Qh, Ql, Kh, Kl, Mrow, Pbuf, lpart);
  hipLaunchKernelGGL(combine_kernel, dim3(32), dim3(256), 0, stream, lpart, lfin);
  hipLaunchKernelGGL(pv_kernel, dim3(512), dim3(256), 0, stream, Pbuf, Vt, lfin, out);
}

// Round 4
// 161.594 us; speedup vs baseline: 1.4665x; 1.0326x over previous
//
#include <hip/hip_runtime.h>
#include <cstdint>
#include <cstddef>

// Problem constants
#define NB 4
#define SS 2048
#define DM 1024
#define DH 64
#define MROWS (NB*SS)      // 8192
#define NALL  (2*DH + DM)  // 1152

typedef __attribute__((ext_vector_type(8))) short bf16x8;
typedef __attribute__((ext_vector_type(4))) float f32x4;
typedef __attribute__((ext_vector_type(4))) unsigned short us4;

__device__ __forceinline__ unsigned short f2bf(float f){
  unsigned u = __builtin_bit_cast(unsigned, f);
  u = (u + 0x7fffu + ((u >> 16) & 1u)) >> 16;   // RNE
  return (unsigned short)u;
}
__device__ __forceinline__ float bf2f(unsigned short h){
  unsigned u = ((unsigned)h) << 16;
  return __builtin_bit_cast(float, u);
}
__device__ __forceinline__ f32x4 mfma16(bf16x8 a, bf16x8 b, f32x4 c){
  return __builtin_amdgcn_mfma_f32_16x16x32_bf16(a, b, c, 0, 0, 0);
}

// ---------------- prep: split x into bf16 hi/lo ----------------
__global__ void prep_x_kernel(const float* __restrict__ x,
                              unsigned short* __restrict__ xh,
                              unsigned short* __restrict__ xl){
  const int n4 = MROWS*DM/4;
  for (int i = blockIdx.x*blockDim.x + threadIdx.x; i < n4; i += gridDim.x*blockDim.x){
    float4 v = reinterpret_cast<const float4*>(x)[i];
    float f[4] = {v.x, v.y, v.z, v.w};
    us4 h, lo;
    #pragma unroll
    for (int j = 0; j < 4; ++j){
      unsigned short hh = f2bf(f[j]);
      h[j]  = hh;
      lo[j] = f2bf(f[j] - bf2f(hh));
    }
    reinterpret_cast<us4*>(xh)[i] = h;
    reinterpret_cast<us4*>(xl)[i] = lo;
  }
}

// ---------------- prep: weights + bias ----------------
__global__ void prep_w_kernel(const float* __restrict__ wq, const float* __restrict__ wk,
                              const float* __restrict__ wv,
                              const float* __restrict__ bq, const float* __restrict__ bk,
                              const float* __restrict__ bv,
                              unsigned short* __restrict__ Whi, unsigned short* __restrict__ Wlo,
                              float* __restrict__ bias_all){
  const int n = NALL*DM;
  for (int i = blockIdx.x*blockDim.x + threadIdx.x; i < n; i += gridDim.x*blockDim.x){
    const int r = i >> 10, c = i & 1023;
    float v;
    if (r < 64)       v = wq[r*1024 + c];
    else if (r < 128) v = wk[(r-64)*1024 + c];
    else              v = wv[(r-128)*1024 + c];
    const unsigned short h = f2bf(v);
    Whi[i] = h;
    if (r < 128) Wlo[i] = f2bf(v - bf2f(h));
    if (i < NALL) bias_all[i] = (i < 64) ? bq[i] : (i < 128) ? bk[i-64] : bv[i-128];
  }
}

// ---------------- QKV GEMM, split-K balanced version ----------------
// Grid 704 = 64 mtiles x 11 equal jobs (all 32 k-steps):
//   j 0..7  : V ntile j   -> Vt (bias fused)
//   j 8..10 : QK pass j-8 -> f32 partial QKpart[p]  (p0=xh.Whi, p1=xh.Wlo, p2=xl.Whi)
__global__ __launch_bounds__(256) void qkv_split_kernel(
    const unsigned short* __restrict__ xh, const unsigned short* __restrict__ xl,
    const unsigned short* __restrict__ Whi, const unsigned short* __restrict__ Wlo,
    const float* __restrict__ bias_all,
    unsigned short* __restrict__ Vt, float* __restrict__ QKpart)
{
  __shared__ unsigned short tA[128*32];
  __shared__ unsigned short tB[128*32];
  const int bx = blockIdx.x;
  const int mtile = bx / 11;
  const int j = bx % 11;
  const int m0 = mtile*128;
  const int tid = threadIdx.x;
  const int l = tid & 63, w = tid >> 6;
  const int lr = l >> 4, lc = l & 15;
  const int wr = w >> 1, wc = w & 1;

  const unsigned short* Ab;
  const unsigned short* Bb;
  if (j < 8){ Ab = xh; Bb = Whi + (size_t)(j+1)*128*DM; }
  else {
    const int p = j - 8;
    Ab = (p == 2) ? xl : xh;
    Bb = (p == 1) ? Wlo : Whi;
  }

  f32x4 acc[4][4] = {};
  for (int k0 = 0; k0 < DM; k0 += 32){
    __syncthreads();
    #pragma unroll
    for (int p = 0; p < 2; ++p){
      const int c   = tid + p*256;
      const int row = c >> 2, kq = c & 3;
      const unsigned short* ga = Ab + ((size_t)(m0+row)*DM + k0 + kq*8);
      const unsigned short* gb = Bb + ((size_t)row*DM     + k0 + kq*8);
      const int lbase = w*1024 + p*4096;
      __builtin_amdgcn_global_load_lds(
          (const __attribute__((address_space(1))) void*)ga,
          (__attribute__((address_space(3))) void*)((char*)tA + lbase), 16, 0, 0);
      __builtin_amdgcn_global_load_lds(
          (const __attribute__((address_space(1))) void*)gb,
          (__attribute__((address_space(3))) void*)((char*)tB + lbase), 16, 0, 0);
    }
    __syncthreads();
    bf16x8 af[4], bfr[4];
    #pragma unroll
    for (int mi = 0; mi < 4; ++mi){
      const int r = wr*64 + mi*16 + lc;
      af[mi] = *reinterpret_cast<const bf16x8*>((const char*)tA + r*64 + lr*16);
    }
    #pragma unroll
    for (int ni = 0; ni < 4; ++ni){
      const int r = wc*64 + ni*16 + lc;
      bfr[ni] = *reinterpret_cast<const bf16x8*>((const char*)tB + r*64 + lr*16);
    }
    #pragma unroll
    for (int mi = 0; mi < 4; ++mi)
      #pragma unroll
      for (int ni = 0; ni < 4; ++ni)
        acc[mi][ni] = mfma16(af[mi], bfr[ni], acc[mi][ni]);
  }

  if (j < 8){
    const int n0 = (j+1)*128;
    #pragma unroll
    for (int ni = 0; ni < 4; ++ni){
      const int col = n0 + wc*64 + ni*16 + lc;
      const float bias = bias_all[col];
      const int vc = col - 128;
      #pragma unroll
      for (int mi = 0; mi < 4; ++mi){
        const int rowb = m0 + wr*64 + mi*16 + lr*4;
        const int b  = rowb >> 11;
        const int s  = rowb & 2047;
        us4 pk;
        #pragma unroll
        for (int i = 0; i < 4; ++i) pk[i] = f2bf(acc[mi][ni][i] + bias);
        *reinterpret_cast<us4*>(&Vt[((size_t)b*DM + vc)*SS + s]) = pk;
      }
    }
  } else {
    float* dst = QKpart + (size_t)(j-8)*MROWS*128;
    #pragma unroll
    for (int mi = 0; mi < 4; ++mi)
      #pragma unroll
      for (int i = 0; i < 4; ++i){
        const int row = m0 + wr*64 + mi*16 + lr*4 + i;
        #pragma unroll
        for (int ni = 0; ni < 4; ++ni){
          const int col = wc*64 + ni*16 + lc;
          dst[(size_t)row*128 + col] = acc[mi][ni][i];
        }
      }
  }
}

// ---------------- combine the 3 QK partials -> Qh/Ql/Kh/Kl ----------------
__global__ __launch_bounds__(256) void qk_combine_kernel(
    const float* __restrict__ QKpart, const float* __restrict__ bias_all,
    unsigned short* __restrict__ Qh, unsigned short* __restrict__ Ql,
    unsigned short* __restrict__ Kh, unsigned short* __restrict__ Kl)
{
  const int t = blockIdx.x*256 + threadIdx.x;    // 0..262143 -> (row, c4)
  const int row = t >> 5, c4 = t & 31;
  const int col0 = c4*4;
  us4 h, lo;
  #pragma unroll
  for (int i = 0; i < 4; ++i){
    const int col = col0 + i;
    const size_t o = (size_t)row*128 + col;
    float s = QKpart[o] + QKpart[(size_t)MROWS*128 + o]
            + QKpart[(size_t)2*MROWS*128 + o] + bias_all[col];
    const unsigned short hh = f2bf(s);
    h[i]  = hh;
    lo[i] = f2bf(s - bf2f(hh));
  }
  if (col0 < 64){
    *reinterpret_cast<us4*>(&Qh[(size_t)row*DH + col0]) = h;
    *reinterpret_cast<us4*>(&Ql[(size_t)row*DH + col0]) = lo;
  } else {
    *reinterpret_cast<us4*>(&Kh[(size_t)row*DH + col0 - 64]) = h;
    *reinterpret_cast<us4*>(&Kl[(size_t)row*DH + col0 - 64]) = lo;
  }
}

// ---------------- QKV GEMM fallback (3-pass, used only if ws too small) ----------------
__global__ __launch_bounds__(256) void qkv_gemm_kernel(
    const unsigned short* __restrict__ xh, const unsigned short* __restrict__ xl,
    const unsigned short* __restrict__ Whi, const unsigned short* __restrict__ Wlo,
    const float* __restrict__ bias_all,
    unsigned short* __restrict__ Qh, unsigned short* __restrict__ Ql,
    unsigned short* __restrict__ Kh, unsigned short* __restrict__ Kl,
    unsigned short* __restrict__ Vt)
{
  __shared__ unsigned short tA[128*32];
  __shared__ unsigned short tB[128*32];
  const int bx = blockIdx.x;
  const int mtile = bx & 63;
  const int ntile = bx >> 6;
  const int m0 = mtile*128, n0 = ntile*128;
  const int tid = threadIdx.x;
  const int l = tid & 63, w = tid >> 6;
  const int lr = l >> 4, lc = l & 15;
  const int wr = w >> 1, wc = w & 1;

  f32x4 acc[4][4] = {};
  const int npass = (ntile == 0) ? 3 : 1;
  for (int pass = 0; pass < npass; ++pass){
    const unsigned short* Ab = (pass == 2) ? xl : xh;
    const unsigned short* Bb = (pass == 1) ? Wlo : (Whi + (size_t)n0*DM);
    for (int k0 = 0; k0 < DM; k0 += 32){
      __syncthreads();
      #pragma unroll
      for (int p = 0; p < 2; ++p){
        const int c   = tid + p*256;
        const int row = c >> 2, kq = c & 3;
        const unsigned short* ga = Ab + ((size_t)(m0+row)*DM + k0 + kq*8);
        const unsigned short* gb = Bb + ((size_t)row*DM     + k0 + kq*8);
        const int lbase = w*1024 + p*4096;
        __builtin_amdgcn_global_load_lds(
            (const __attribute__((address_space(1))) void*)ga,
            (__attribute__((address_space(3))) void*)((char*)tA + lbase), 16, 0, 0);
        __builtin_amdgcn_global_load_lds(
            (const __attribute__((address_space(1))) void*)gb,
            (__attribute__((address_space(3))) void*)((char*)tB + lbase), 16, 0, 0);
      }
      __syncthreads();
      bf16x8 af[4], bfr[4];
      #pragma unroll
      for (int mi = 0; mi < 4; ++mi){
        const int r = wr*64 + mi*16 + lc;
        af[mi] = *reinterpret_cast<const bf16x8*>((const char*)tA + r*64 + lr*16);
      }
      #pragma unroll
      for (int ni = 0; ni < 4; ++ni){
        const int r = wc*64 + ni*16 + lc;
        bfr[ni] = *reinterpret_cast<const bf16x8*>((const char*)tB + r*64 + lr*16);
      }
      #pragma unroll
      for (int mi = 0; mi < 4; ++mi)
        #pragma unroll
        for (int ni = 0; ni < 4; ++ni)
          acc[mi][ni] = mfma16(af[mi], bfr[ni], acc[mi][ni]);
    }
  }

  #pragma unroll
  for (int ni = 0; ni < 4; ++ni){
    const int col = n0 + wc*64 + ni*16 + lc;
    const float bias = bias_all[col];
    #pragma unroll
    for (int mi = 0; mi < 4; ++mi){
      const int rowb = m0 + wr*64 + mi*16 + lr*4;
      if (ntile > 0){
        const int vc = col - 128;
        const int b  = rowb >> 11;
        const int s  = rowb & 2047;
        us4 pk;
        #pragma unroll
        for (int i = 0; i < 4; ++i) pk[i] = f2bf(acc[mi][ni][i] + bias);
        *reinterpret_cast<us4*>(&Vt[((size_t)b*DM + vc)*SS + s]) = pk;
      } else {
        #pragma unroll
        for (int i = 0; i < 4; ++i){
          const int row = rowb + i;
          const float v = acc[mi][ni][i] + bias;
          const unsigned short h   = f2bf(v);
          const unsigned short lo2 = f2bf(v - bf2f(h));
          if (col < DH){
            Qh[(size_t)row*DH + col] = h;
            Ql[(size_t)row*DH + col] = lo2;
          } else {
            Kh[(size_t)row*DH + col - DH] = h;
            Kl[(size_t)row*DH + col - DH] = lo2;
          }
        }
      }
    }
  }
}

// ---------------- diag: per-row softmax anchor M_r = q_r.k_r + 20, zero lpart ----------------
__global__ __launch_bounds__(256) void diag_kernel(
    const unsigned short* __restrict__ Qh, const unsigned short* __restrict__ Ql,
    const unsigned short* __restrict__ Kh, const unsigned short* __restrict__ Kl,
    float* __restrict__ Mrow, float* __restrict__ lpart)
{
  const int r = blockIdx.x*256 + threadIdx.x;   // 0..8191
  float dot = 0.f;
  #pragma unroll
  for (int c = 0; c < 8; ++c){
    bf16x8 a  = *reinterpret_cast<const bf16x8*>(Qh + (size_t)r*DH + c*8);
    bf16x8 al = *reinterpret_cast<const bf16x8*>(Ql + (size_t)r*DH + c*8);
    bf16x8 bh = *reinterpret_cast<const bf16x8*>(Kh + (size_t)r*DH + c*8);
    bf16x8 bl = *reinterpret_cast<const bf16x8*>(Kl + (size_t)r*DH + c*8);
    #pragma unroll
    for (int j = 0; j < 8; ++j)
      dot += (bf2f((unsigned short)a[j]) + bf2f((unsigned short)al[j])) *
             (bf2f((unsigned short)bh[j]) + bf2f((unsigned short)bl[j]));
  }
  Mrow[r] = dot + 20.0f;
  #pragma unroll
  for (int kc = 0; kc < 8; ++kc) lpart[(size_t)r*8 + kc] = 0.f;
}

// ---------------- scores: P = exp(S - M_r) bf16, per-chunk row sums ----------------
__global__ __launch_bounds__(512) void scores_kernel(
    const unsigned short* __restrict__ Qh, const unsigned short* __restrict__ Ql,
    const unsigned short* __restrict__ Kh, const unsigned short* __restrict__ Kl,
    const float* __restrict__ Mrow,
    unsigned short* __restrict__ Pbuf, float* __restrict__ lpart)
{
  __shared__ float ws_s[8][32];
  const int t = blockIdx.x, b = blockIdx.y;
  int g = 0;
  while (g < 7 && 4*(g+1)*(g+2) <= t) ++g;
  const int base = 4*g*(g+1);
  const int qt = 8*g + (t - base)/(g+1);
  const int kc = (t - base)%(g+1);
  const int q0 = qt*32, kbase = kc*256;
  const int tid = threadIdx.x, l = tid & 63, w = tid >> 6;
  const int lr = l >> 4, lc = l & 15;
  const int kw0 = kbase + w*32;
  const float L2E = 1.4426950408889634f;

  bf16x8 qh[2][2], qlo[2][2], kh[2][2], kl2[2][2];
  #pragma unroll
  for (int qi = 0; qi < 2; ++qi)
    #pragma unroll
    for (int ks = 0; ks < 2; ++ks){
      const size_t off = (size_t)(b*SS + q0 + qi*16 + lc)*DH + ks*32 + lr*8;
      qh[qi][ks]  = *reinterpret_cast<const bf16x8*>(&Qh[off]);
      qlo[qi][ks] = *reinterpret_cast<const bf16x8*>(&Ql[off]);
    }
  #pragma unroll
  for (int ki = 0; ki < 2; ++ki)
    #pragma unroll
    for (int ks = 0; ks < 2; ++ks){
      const size_t off = (size_t)(b*SS + kw0 + ki*16 + lc)*DH + ks*32 + lr*8;
      kh[ki][ks]  = *reinterpret_cast<const bf16x8*>(&Kh[off]);
      kl2[ki][ks] = *reinterpret_cast<const bf16x8*>(&Kl[off]);
    }

  f32x4 sa[2][2] = {};
  #pragma unroll
  for (int qi = 0; qi < 2; ++qi)
    #pragma unroll
    for (int ki = 0; ki < 2; ++ki)
      #pragma unroll
      for (int ks = 0; ks < 2; ++ks){
        sa[qi][ki] = mfma16(qh[qi][ks],  kh[ki][ks],  sa[qi][ki]);
        sa[qi][ki] = mfma16(qh[qi][ks],  kl2[ki][ks], sa[qi][ki]);
        sa[qi][ki] = mfma16(qlo[qi][ks], kh[ki][ks],  sa[qi][ki]);
      }

  float Mv[2][4];
  #pragma unroll
  for (int qi = 0; qi < 2; ++qi)
    #pragma unroll
    for (int i = 0; i < 4; ++i)
      Mv[qi][i] = Mrow[b*SS + q0 + qi*16 + lr*4 + i];

  const bool diagblk = (kc == (qt >> 3));
  float psum[2][4] = {};
  #pragma unroll
  for (int qi = 0; qi < 2; ++qi)
    #pragma unroll
    for (int ki = 0; ki < 2; ++ki)
      #pragma unroll
      for (int i = 0; i < 4; ++i){
        const int qrow = qi*16 + lr*4 + i;
        const int kcol = w*32 + ki*16 + lc;
        float p;
        if (diagblk && (kbase + kcol > q0 + qrow)) p = 0.f;
        else p = exp2f((sa[qi][ki][i] - Mv[qi][i])*L2E);
        Pbuf[(size_t)(b*SS + q0 + qrow)*SS + kbase + kcol] = f2bf(p);
        psum[qi][i] += p;
      }

  #pragma unroll
  for (int qi = 0; qi < 2; ++qi)
    #pragma unroll
    for (int i = 0; i < 4; ++i){
      float s = psum[qi][i];
      #pragma unroll
      for (int m = 1; m < 16; m <<= 1) s += __shfl_xor(s, m);
      psum[qi][i] = s;
    }
  if (lc == 0){
    #pragma unroll
    for (int qi = 0; qi < 2; ++qi)
      #pragma unroll
      for (int i = 0; i < 4; ++i)
        ws_s[w][qi*16 + lr*4 + i] = psum[qi][i];
  }
  __syncthreads();
  if (tid < 32){
    float s = 0.f;
    #pragma unroll
    for (int w2 = 0; w2 < 8; ++w2) s += ws_s[w2][tid];
    lpart[(size_t)(b*SS + q0 + tid)*8 + kc] = s;
  }
}

// ---------------- combine: l_r = sum of chunk partials ----------------
__global__ __launch_bounds__(256) void combine_kernel(const float* __restrict__ lpart,
                                                      float* __restrict__ lfin){
  const int r = blockIdx.x*256 + threadIdx.x;
  float s = 0.f;
  #pragma unroll
  for (int kc = 0; kc < 8; ++kc) s += lpart[(size_t)r*8 + kc];
  lfin[r] = s;
}

// ---------------- PV GEMM (m97 structure): out = (P @ V) / l ----------------
__global__ __launch_bounds__(256) void pv_kernel(
    const unsigned short* __restrict__ Pbuf, const unsigned short* __restrict__ Vt,
    const float* __restrict__ lfin, float* __restrict__ out)
{
  __shared__ unsigned short tA[128*32];
  __shared__ unsigned short tB[128*32];
  const int bx = blockIdx.x;           // 0..511
  const int nt = bx & 7;
  const int t2 = bx >> 3;              // 0..63
  const int b  = t2 & 3;
  const int mt = 15 - (t2 >> 2);       // heavy (large-K) tiles first
  const int m0 = mt*128, n0 = nt*128;
  const int tid = threadIdx.x;
  const int l = tid & 63, w = tid >> 6;
  const int lr = l >> 4, lc = l & 15;
  const int wr = w >> 1, wc = w & 1;

  const unsigned short* Ab = Pbuf + (size_t)(b*SS + m0)*SS;
  const unsigned short* Bb = Vt   + (size_t)(b*DM + n0)*SS;

  f32x4 acc[4][4] = {};
  const int kend = (mt/2 + 1)*256;
  for (int k0 = 0; k0 < kend; k0 += 32){
    __syncthreads();
    #pragma unroll
    for (int p = 0; p < 2; ++p){
      const int c   = tid + p*256;
      const int row = c >> 2, kq = c & 3;
      const unsigned short* ga = Ab + ((size_t)row*SS + k0 + kq*8);
      const unsigned short* gb = Bb + ((size_t)row*SS + k0 + kq*8);
      const int lbase = w*1024 + p*4096;
      __builtin_amdgcn_global_load_lds(
          (const __attribute__((address_space(1))) void*)ga,
          (__attribute__((address_space(3))) void*)((char*)tA + lbase), 16, 0, 0);
      __builtin_amdgcn_global_load_lds(
          (const __attribute__((address_space(1))) void*)gb,
          (__attribute__((address_space(3))) void*)((char*)tB + lbase), 16, 0, 0);
    }
    __syncthreads();
    bf16x8 af[4], bfr[4];
    #pragma unroll
    for (int mi = 0; mi < 4; ++mi){
      const int r = wr*64 + mi*16 + lc;
      af[mi] = *reinterpret_cast<const bf16x8*>((const char*)tA + r*64 + lr*16);
    }
    #pragma unroll
    for (int ni = 0; ni < 4; ++ni){
      const int r = wc*64 + ni*16 + lc;
      bfr[ni] = *reinterpret_cast<const bf16x8*>((const char*)tB + r*64 + lr*16);
    }
    #pragma unroll
    for (int mi = 0; mi < 4; ++mi)
      #pragma unroll
      for (int ni = 0; ni < 4; ++ni)
        acc[mi][ni] = mfma16(af[mi], bfr[ni], acc[mi][ni]);
  }

  #pragma unroll
  for (int mi = 0; mi < 4; ++mi){
    #pragma unroll
    for (int i = 0; i < 4; ++i){
      const int row = m0 + wr*64 + mi*16 + lr*4 + i;
      const float linv = 1.0f / lfin[b*SS + row];
      #pragma unroll
      for (int ni = 0; ni < 4; ++ni){
        const int col = n0 + wc*64 + ni*16 + lc;
        out[(size_t)(b*SS + row)*DM + col] = acc[mi][ni][i]*linv;
      }
    }
  }
}

// ---------------- launcher ----------------
extern "C" void kernel_launch(void* const* d_in, const int* in_sizes, int n_in,
                              void* d_out, int out_size, void* d_ws, size_t ws_size,
                              hipStream_t stream)
{
  const float* x  = (const float*)d_in[0];
  const float* wq = (const float*)d_in[1];
  const float* bq = (const float*)d_in[2];
  const float* wk = (const float*)d_in[3];
  const float* bk = (const float*)d_in[4];
  const float* wv = (const float*)d_in[5];
  const float* bv = (const float*)d_in[6];
  float* out = (float*)d_out;

  char* ws = (char*)d_ws;
  unsigned short* xh  = (unsigned short*)(ws + 0);          // 16,777,216
  unsigned short* xl  = (unsigned short*)(ws + 16777216);   // 16,777,216
  unsigned short* Pbuf= (unsigned short*)(ws + 0);          // 33,554,432 (alias)
  unsigned short* Whi = (unsigned short*)(ws + 33554432);   //  2,359,296
  unsigned short* Wlo = (unsigned short*)(ws + 35913728);   //    262,144
  float* bias_all     = (float*)(ws + 36175872);            //      4,608
  unsigned short* Qh  = (unsigned short*)(ws + 36180480);   //  1,048,576
  unsigned short* Ql  = (unsigned short*)(ws + 37229056);   //  1,048,576
  unsigned short* Kh  = (unsigned short*)(ws + 38277632);   //  1,048,576
  unsigned short* Kl  = (unsigned short*)(ws + 39326208);   //  1,048,576
  unsigned short* Vt  = (unsigned short*)(ws + 40374784);   // 16,777,216
  float* Mrow         = (float*)(ws + 57152000);            //     32,768
  float* lpart        = (float*)(ws + 57184768);            //    262,144
  float* lfin         = (float*)(ws + 57446912);            //     32,768
  const size_t QKPART_OFF = 57479680;
  float* QKpart       = (float*)(ws + QKPART_OFF);          // 12,582,912
  const size_t NEED = QKPART_OFF + (size_t)3*MROWS*128*4;   // 70,062,592

  hipLaunchKernelGGL(prep_x_kernel, dim3(2048), dim3(256), 0, stream, x, xh, xl);
  hipLaunchKernelGGL(prep_w_kernel, dim3(1184), dim3(256), 0, stream,
                     wq, wk, wv, bq, bk, bv, Whi, Wlo, bias_all);
  if (ws_size >= NEED){
    hipLaunchKernelGGL(qkv_split_kernel, dim3(704), dim3(256), 0, stream,
                       xh, xl, Whi, Wlo, bias_all, Vt, QKpart);
    hipLaunchKernelGGL(qk_combine_kernel, dim3(1024), dim3(256), 0, stream,
                       QKpart, bias_all, Qh, Ql, Kh, Kl);
  } else {
    hipLaunchKernelGGL(qkv_gemm_kernel, dim3(576), dim3(256), 0, stream,
                       xh, xl, Whi, Wlo, bias_all, Qh, Ql, Kh, Kl, Vt);
  }
  hipLaunchKernelGGL(diag_kernel, dim3(32), dim3(256), 0, stream,
                     Qh, Ql, Kh, Kl, Mrow, lpart);
  hipLaunchKernelGGL(scores_kernel, dim3(288, 4), dim3(512), 0, stream,
                     Qh, Ql, Kh, Kl, Mrow, Pbuf, lpart);
  hipLaunchKernelGGL(combine_kernel, dim3(32), dim3(256), 0, stream, lpart, lfin);
  hipLaunchKernelGGL(pv_kernel, dim3(512), dim3(256), 0, stream, Pbuf, Vt, lfin, out);
}

// Round 5
// 152.670 us; speedup vs baseline: 1.5522x; 1.0585x over previous
//
#include <hip/hip_runtime.h>
#include <cstdint>
#include <cstddef>

// Problem constants
#define NB 4
#define SS 2048
#define DM 1024
#define DH 64
#define MROWS (NB*SS)      // 8192
#define NALL  (2*DH + DM)  // 1152

typedef __attribute__((ext_vector_type(8))) short bf16x8;
typedef __attribute__((ext_vector_type(4))) float f32x4;
typedef __attribute__((ext_vector_type(4))) unsigned short us4;

__device__ __forceinline__ unsigned short f2bf(float f){
  unsigned u = __builtin_bit_cast(unsigned, f);
  u = (u + 0x7fffu + ((u >> 16) & 1u)) >> 16;   // RNE
  return (unsigned short)u;
}
__device__ __forceinline__ float bf2f(unsigned short h){
  unsigned u = ((unsigned)h) << 16;
  return __builtin_bit_cast(float, u);
}
__device__ __forceinline__ f32x4 mfma16(bf16x8 a, bf16x8 b, f32x4 c){
  return __builtin_amdgcn_mfma_f32_16x16x32_bf16(a, b, c, 0, 0, 0);
}

// ---------------- prep: split x into bf16 hi/lo ----------------
__global__ void prep_x_kernel(const float* __restrict__ x,
                              unsigned short* __restrict__ xh,
                              unsigned short* __restrict__ xl){
  const int n4 = MROWS*DM/4;
  for (int i = blockIdx.x*blockDim.x + threadIdx.x; i < n4; i += gridDim.x*blockDim.x){
    float4 v = reinterpret_cast<const float4*>(x)[i];
    float f[4] = {v.x, v.y, v.z, v.w};
    us4 h, lo;
    #pragma unroll
    for (int j = 0; j < 4; ++j){
      unsigned short hh = f2bf(f[j]);
      h[j]  = hh;
      lo[j] = f2bf(f[j] - bf2f(hh));
    }
    reinterpret_cast<us4*>(xh)[i] = h;
    reinterpret_cast<us4*>(xl)[i] = lo;
  }
}

// ---------------- prep: weights + bias ----------------
__global__ void prep_w_kernel(const float* __restrict__ wq, const float* __restrict__ wk,
                              const float* __restrict__ wv,
                              const float* __restrict__ bq, const float* __restrict__ bk,
                              const float* __restrict__ bv,
                              unsigned short* __restrict__ Whi, unsigned short* __restrict__ Wlo,
                              float* __restrict__ bias_all){
  const int n = NALL*DM;
  for (int i = blockIdx.x*blockDim.x + threadIdx.x; i < n; i += gridDim.x*blockDim.x){
    const int r = i >> 10, c = i & 1023;
    float v;
    if (r < 64)       v = wq[r*1024 + c];
    else if (r < 128) v = wk[(r-64)*1024 + c];
    else              v = wv[(r-128)*1024 + c];
    const unsigned short h = f2bf(v);
    Whi[i] = h;
    if (r < 128) Wlo[i] = f2bf(v - bf2f(h));
    if (i < NALL) bias_all[i] = (i < 64) ? bq[i] : (i < 128) ? bk[i-64] : bv[i-128];
  }
}

// ---------------- QKV GEMM, split-K balanced + XCD-clustered ----------------
// 704 blocks = 64 mtiles x 11 equal jobs.
// XCD-clustered decode (HW round-robins bx%8 across XCDs): XCD x owns
// mtiles [8x, 8x+8) for all 11 jobs -> per-XCD per-k-step working set
// ~216 KB << 4 MB L2, so staging reads hit L2 instead of L3/HBM.
//   j 0..7  : V ntile j   -> Vt (bias fused)
//   j 8..10 : QK pass j-8 -> f32 partial QKpart[p]  (p0=xh.Whi, p1=xh.Wlo, p2=xl.Whi)
__global__ __launch_bounds__(256) void qkv_split_kernel(
    const unsigned short* __restrict__ xh, const unsigned short* __restrict__ xl,
    const unsigned short* __restrict__ Whi, const unsigned short* __restrict__ Wlo,
    const float* __restrict__ bias_all,
    unsigned short* __restrict__ Vt, float* __restrict__ QKpart)
{
  __shared__ unsigned short tA[128*32];
  __shared__ unsigned short tB[128*32];
  const int bx = blockIdx.x;
  const int xcd  = bx & 7;
  const int slot = bx >> 3;              // 0..87
  const int mtile = xcd*8 + (slot & 7);  // XCD x -> mtiles 8x..8x+7
  const int j = slot >> 3;               // 0..10
  const int m0 = mtile*128;
  const int tid = threadIdx.x;
  const int l = tid & 63, w = tid >> 6;
  const int lr = l >> 4, lc = l & 15;
  const int wr = w >> 1, wc = w & 1;

  const unsigned short* Ab;
  const unsigned short* Bb;
  if (j < 8){ Ab = xh; Bb = Whi + (size_t)(j+1)*128*DM; }
  else {
    const int p = j - 8;
    Ab = (p == 2) ? xl : xh;
    Bb = (p == 1) ? Wlo : Whi;
  }

  f32x4 acc[4][4] = {};
  for (int k0 = 0; k0 < DM; k0 += 32){
    __syncthreads();
    #pragma unroll
    for (int p = 0; p < 2; ++p){
      const int c   = tid + p*256;
      const int row = c >> 2, kq = c & 3;
      const unsigned short* ga = Ab + ((size_t)(m0+row)*DM + k0 + kq*8);
      const unsigned short* gb = Bb + ((size_t)row*DM     + k0 + kq*8);
      const int lbase = w*1024 + p*4096;
      __builtin_amdgcn_global_load_lds(
          (const __attribute__((address_space(1))) void*)ga,
          (__attribute__((address_space(3))) void*)((char*)tA + lbase), 16, 0, 0);
      __builtin_amdgcn_global_load_lds(
          (const __attribute__((address_space(1))) void*)gb,
          (__attribute__((address_space(3))) void*)((char*)tB + lbase), 16, 0, 0);
    }
    __syncthreads();
    bf16x8 af[4], bfr[4];
    #pragma unroll
    for (int mi = 0; mi < 4; ++mi){
      const int r = wr*64 + mi*16 + lc;
      af[mi] = *reinterpret_cast<const bf16x8*>((const char*)tA + r*64 + lr*16);
    }
    #pragma unroll
    for (int ni = 0; ni < 4; ++ni){
      const int r = wc*64 + ni*16 + lc;
      bfr[ni] = *reinterpret_cast<const bf16x8*>((const char*)tB + r*64 + lr*16);
    }
    #pragma unroll
    for (int mi = 0; mi < 4; ++mi)
      #pragma unroll
      for (int ni = 0; ni < 4; ++ni)
        acc[mi][ni] = mfma16(af[mi], bfr[ni], acc[mi][ni]);
  }

  if (j < 8){
    const int n0 = (j+1)*128;
    #pragma unroll
    for (int ni = 0; ni < 4; ++ni){
      const int col = n0 + wc*64 + ni*16 + lc;
      const float bias = bias_all[col];
      const int vc = col - 128;
      #pragma unroll
      for (int mi = 0; mi < 4; ++mi){
        const int rowb = m0 + wr*64 + mi*16 + lr*4;
        const int b  = rowb >> 11;
        const int s  = rowb & 2047;
        us4 pk;
        #pragma unroll
        for (int i = 0; i < 4; ++i) pk[i] = f2bf(acc[mi][ni][i] + bias);
        *reinterpret_cast<us4*>(&Vt[((size_t)b*DM + vc)*SS + s]) = pk;
      }
    }
  } else {
    float* dst = QKpart + (size_t)(j-8)*MROWS*128;
    #pragma unroll
    for (int mi = 0; mi < 4; ++mi)
      #pragma unroll
      for (int i = 0; i < 4; ++i){
        const int row = m0 + wr*64 + mi*16 + lr*4 + i;
        #pragma unroll
        for (int ni = 0; ni < 4; ++ni){
          const int col = wc*64 + ni*16 + lc;
          dst[(size_t)row*128 + col] = acc[mi][ni][i];
        }
      }
  }
}

// ---------------- combine the 3 QK partials -> Qh/Ql/Kh/Kl ----------------
__global__ __launch_bounds__(256) void qk_combine_kernel(
    const float* __restrict__ QKpart, const float* __restrict__ bias_all,
    unsigned short* __restrict__ Qh, unsigned short* __restrict__ Ql,
    unsigned short* __restrict__ Kh, unsigned short* __restrict__ Kl)
{
  const int t = blockIdx.x*256 + threadIdx.x;    // 0..262143 -> (row, c4)
  const int row = t >> 5, c4 = t & 31;
  const int col0 = c4*4;
  us4 h, lo;
  #pragma unroll
  for (int i = 0; i < 4; ++i){
    const int col = col0 + i;
    const size_t o = (size_t)row*128 + col;
    float s = QKpart[o] + QKpart[(size_t)MROWS*128 + o]
            + QKpart[(size_t)2*MROWS*128 + o] + bias_all[col];
    const unsigned short hh = f2bf(s);
    h[i]  = hh;
    lo[i] = f2bf(s - bf2f(hh));
  }
  if (col0 < 64){
    *reinterpret_cast<us4*>(&Qh[(size_t)row*DH + col0]) = h;
    *reinterpret_cast<us4*>(&Ql[(size_t)row*DH + col0]) = lo;
  } else {
    *reinterpret_cast<us4*>(&Kh[(size_t)row*DH + col0 - 64]) = h;
    *reinterpret_cast<us4*>(&Kl[(size_t)row*DH + col0 - 64]) = lo;
  }
}

// ---------------- QKV GEMM fallback (3-pass, used only if ws too small) ----------------
__global__ __launch_bounds__(256) void qkv_gemm_kernel(
    const unsigned short* __restrict__ xh, const unsigned short* __restrict__ xl,
    const unsigned short* __restrict__ Whi, const unsigned short* __restrict__ Wlo,
    const float* __restrict__ bias_all,
    unsigned short* __restrict__ Qh, unsigned short* __restrict__ Ql,
    unsigned short* __restrict__ Kh, unsigned short* __restrict__ Kl,
    unsigned short* __restrict__ Vt)
{
  __shared__ unsigned short tA[128*32];
  __shared__ unsigned short tB[128*32];
  const int bx = blockIdx.x;
  const int mtile = bx & 63;
  const int ntile = bx >> 6;
  const int m0 = mtile*128, n0 = ntile*128;
  const int tid = threadIdx.x;
  const int l = tid & 63, w = tid >> 6;
  const int lr = l >> 4, lc = l & 15;
  const int wr = w >> 1, wc = w & 1;

  f32x4 acc[4][4] = {};
  const int npass = (ntile == 0) ? 3 : 1;
  for (int pass = 0; pass < npass; ++pass){
    const unsigned short* Ab = (pass == 2) ? xl : xh;
    const unsigned short* Bb = (pass == 1) ? Wlo : (Whi + (size_t)n0*DM);
    for (int k0 = 0; k0 < DM; k0 += 32){
      __syncthreads();
      #pragma unroll
      for (int p = 0; p < 2; ++p){
        const int c   = tid + p*256;
        const int row = c >> 2, kq = c & 3;
        const unsigned short* ga = Ab + ((size_t)(m0+row)*DM + k0 + kq*8);
        const unsigned short* gb = Bb + ((size_t)row*DM     + k0 + kq*8);
        const int lbase = w*1024 + p*4096;
        __builtin_amdgcn_global_load_lds(
            (const __attribute__((address_space(1))) void*)ga,
            (__attribute__((address_space(3))) void*)((char*)tA + lbase), 16, 0, 0);
        __builtin_amdgcn_global_load_lds(
            (const __attribute__((address_space(1))) void*)gb,
            (__attribute__((address_space(3))) void*)((char*)tB + lbase), 16, 0, 0);
      }
      __syncthreads();
      bf16x8 af[4], bfr[4];
      #pragma unroll
      for (int mi = 0; mi < 4; ++mi){
        const int r = wr*64 + mi*16 + lc;
        af[mi] = *reinterpret_cast<const bf16x8*>((const char*)tA + r*64 + lr*16);
      }
      #pragma unroll
      for (int ni = 0; ni < 4; ++ni){
        const int r = wc*64 + ni*16 + lc;
        bfr[ni] = *reinterpret_cast<const bf16x8*>((const char*)tB + r*64 + lr*16);
      }
      #pragma unroll
      for (int mi = 0; mi < 4; ++mi)
        #pragma unroll
        for (int ni = 0; ni < 4; ++ni)
          acc[mi][ni] = mfma16(af[mi], bfr[ni], acc[mi][ni]);
    }
  }

  #pragma unroll
  for (int ni = 0; ni < 4; ++ni){
    const int col = n0 + wc*64 + ni*16 + lc;
    const float bias = bias_all[col];
    #pragma unroll
    for (int mi = 0; mi < 4; ++mi){
      const int rowb = m0 + wr*64 + mi*16 + lr*4;
      if (ntile > 0){
        const int vc = col - 128;
        const int b  = rowb >> 11;
        const int s  = rowb & 2047;
        us4 pk;
        #pragma unroll
        for (int i = 0; i < 4; ++i) pk[i] = f2bf(acc[mi][ni][i] + bias);
        *reinterpret_cast<us4*>(&Vt[((size_t)b*DM + vc)*SS + s]) = pk;
      } else {
        #pragma unroll
        for (int i = 0; i < 4; ++i){
          const int row = rowb + i;
          const float v = acc[mi][ni][i] + bias;
          const unsigned short h   = f2bf(v);
          const unsigned short lo2 = f2bf(v - bf2f(h));
          if (col < DH){
            Qh[(size_t)row*DH + col] = h;
            Ql[(size_t)row*DH + col] = lo2;
          } else {
            Kh[(size_t)row*DH + col - DH] = h;
            Kl[(size_t)row*DH + col - DH] = lo2;
          }
        }
      }
    }
  }
}

// ---------------- diag: per-row softmax anchor M_r = q_r.k_r + 20, zero lpart ----------------
__global__ __launch_bounds__(256) void diag_kernel(
    const unsigned short* __restrict__ Qh, const unsigned short* __restrict__ Ql,
    const unsigned short* __restrict__ Kh, const unsigned short* __restrict__ Kl,
    float* __restrict__ Mrow, float* __restrict__ lpart)
{
  const int r = blockIdx.x*256 + threadIdx.x;   // 0..8191
  float dot = 0.f;
  #pragma unroll
  for (int c = 0; c < 8; ++c){
    bf16x8 a  = *reinterpret_cast<const bf16x8*>(Qh + (size_t)r*DH + c*8);
    bf16x8 al = *reinterpret_cast<const bf16x8*>(Ql + (size_t)r*DH + c*8);
    bf16x8 bh = *reinterpret_cast<const bf16x8*>(Kh + (size_t)r*DH + c*8);
    bf16x8 bl = *reinterpret_cast<const bf16x8*>(Kl + (size_t)r*DH + c*8);
    #pragma unroll
    for (int j = 0; j < 8; ++j)
      dot += (bf2f((unsigned short)a[j]) + bf2f((unsigned short)al[j])) *
             (bf2f((unsigned short)bh[j]) + bf2f((unsigned short)bl[j]));
  }
  Mrow[r] = dot + 20.0f;
  #pragma unroll
  for (int kc = 0; kc < 8; ++kc) lpart[(size_t)r*8 + kc] = 0.f;
}

// ---------------- scores: P = exp(S - M_r) bf16, per-chunk row sums ----------------
__global__ __launch_bounds__(512) void scores_kernel(
    const unsigned short* __restrict__ Qh, const unsigned short* __restrict__ Ql,
    const unsigned short* __restrict__ Kh, const unsigned short* __restrict__ Kl,
    const float* __restrict__ Mrow,
    unsigned short* __restrict__ Pbuf, float* __restrict__ lpart)
{
  __shared__ float ws_s[8][32];
  const int t = blockIdx.x, b = blockIdx.y;
  int g = 0;
  while (g < 7 && 4*(g+1)*(g+2) <= t) ++g;
  const int base = 4*g*(g+1);
  const int qt = 8*g + (t - base)/(g+1);
  const int kc = (t - base)%(g+1);
  const int q0 = qt*32, kbase = kc*256;
  const int tid = threadIdx.x, l = tid & 63, w = tid >> 6;
  const int lr = l >> 4, lc = l & 15;
  const int kw0 = kbase + w*32;
  const float L2E = 1.4426950408889634f;

  bf16x8 qh[2][2], qlo[2][2], kh[2][2], kl2[2][2];
  #pragma unroll
  for (int qi = 0; qi < 2; ++qi)
    #pragma unroll
    for (int ks = 0; ks < 2; ++ks){
      const size_t off = (size_t)(b*SS + q0 + qi*16 + lc)*DH + ks*32 + lr*8;
      qh[qi][ks]  = *reinterpret_cast<const bf16x8*>(&Qh[off]);
      qlo[qi][ks] = *reinterpret_cast<const bf16x8*>(&Ql[off]);
    }
  #pragma unroll
  for (int ki = 0; ki < 2; ++ki)
    #pragma unroll
    for (int ks = 0; ks < 2; ++ks){
      const size_t off = (size_t)(b*SS + kw0 + ki*16 + lc)*DH + ks*32 + lr*8;
      kh[ki][ks]  = *reinterpret_cast<const bf16x8*>(&Kh[off]);
      kl2[ki][ks] = *reinterpret_cast<const bf16x8*>(&Kl[off]);
    }

  f32x4 sa[2][2] = {};
  #pragma unroll
  for (int qi = 0; qi < 2; ++qi)
    #pragma unroll
    for (int ki = 0; ki < 2; ++ki)
      #pragma unroll
      for (int ks = 0; ks < 2; ++ks){
        sa[qi][ki] = mfma16(qh[qi][ks],  kh[ki][ks],  sa[qi][ki]);
        sa[qi][ki] = mfma16(qh[qi][ks],  kl2[ki][ks], sa[qi][ki]);
        sa[qi][ki] = mfma16(qlo[qi][ks], kh[ki][ks],  sa[qi][ki]);
      }

  float Mv[2][4];
  #pragma unroll
  for (int qi = 0; qi < 2; ++qi)
    #pragma unroll
    for (int i = 0; i < 4; ++i)
      Mv[qi][i] = Mrow[b*SS + q0 + qi*16 + lr*4 + i];

  const bool diagblk = (kc == (qt >> 3));
  float psum[2][4] = {};
  #pragma unroll
  for (int qi = 0; qi < 2; ++qi)
    #pragma unroll
    for (int ki = 0; ki < 2; ++ki)
      #pragma unroll
      for (int i = 0; i < 4; ++i){
        const int qrow = qi*16 + lr*4 + i;
        const int kcol = w*32 + ki*16 + lc;
        float p;
        if (diagblk && (kbase + kcol > q0 + qrow)) p = 0.f;
        else p = exp2f((sa[qi][ki][i] - Mv[qi][i])*L2E);
        Pbuf[(size_t)(b*SS + q0 + qrow)*SS + kbase + kcol] = f2bf(p);
        psum[qi][i] += p;
      }

  #pragma unroll
  for (int qi = 0; qi < 2; ++qi)
    #pragma unroll
    for (int i = 0; i < 4; ++i){
      float s = psum[qi][i];
      #pragma unroll
      for (int m = 1; m < 16; m <<= 1) s += __shfl_xor(s, m);
      psum[qi][i] = s;
    }
  if (lc == 0){
    #pragma unroll
    for (int qi = 0; qi < 2; ++qi)
      #pragma unroll
      for (int i = 0; i < 4; ++i)
        ws_s[w][qi*16 + lr*4 + i] = psum[qi][i];
  }
  __syncthreads();
  if (tid < 32){
    float s = 0.f;
    #pragma unroll
    for (int w2 = 0; w2 < 8; ++w2) s += ws_s[w2][tid];
    lpart[(size_t)(b*SS + q0 + tid)*8 + kc] = s;
  }
}

// ---------------- combine: l_r = sum of chunk partials ----------------
__global__ __launch_bounds__(256) void combine_kernel(const float* __restrict__ lpart,
                                                      float* __restrict__ lfin){
  const int r = blockIdx.x*256 + threadIdx.x;
  float s = 0.f;
  #pragma unroll
  for (int kc = 0; kc < 8; ++kc) s += lpart[(size_t)r*8 + kc];
  lfin[r] = s;
}

// ---------------- PV GEMM (m97 structure) + XCD-clustered: out = (P @ V) / l ----------------
// 512 blocks = 64 per XCD. XCD x owns (batch = x>>1, nt-group = x&1):
// its B working set = 4 Vt-slices = 2 MB (L2-resident), and the 4 nt-blocks
// sharing a P A-tile are co-located. Within-XCD: mt paired k/(15-k) per CU
// for equal work. kend = (mt/2+1)*256 covers every row's diagonal chunk,
// whose masked region scores_kernel zero-fills (garbage-safe).
__global__ __launch_bounds__(256) void pv_kernel(
    const unsigned short* __restrict__ Pbuf, const unsigned short* __restrict__ Vt,
    const float* __restrict__ lfin, float* __restrict__ out)
{
  __shared__ unsigned short tA[128*32];
  __shared__ unsigned short tB[128*32];
  const int bx = blockIdx.x;           // 0..511
  const int xcd  = bx & 7;
  const int slot = bx >> 3;            // 0..63
  const int b   = xcd >> 1;
  const int ntg = xcd & 1;
  const int nt  = ntg*4 + (slot & 3);
  const int mt  = (slot < 32) ? (15 - (slot >> 2)) : ((slot - 32) >> 2);
  const int m0 = mt*128, n0 = nt*128;
  const int tid = threadIdx.x;
  const int l = tid & 63, w = tid >> 6;
  const int lr = l >> 4, lc = l & 15;
  const int wr = w >> 1, wc = w & 1;

  const unsigned short* Ab = Pbuf + (size_t)(b*SS + m0)*SS;
  const unsigned short* Bb = Vt   + (size_t)(b*DM + n0)*SS;

  f32x4 acc[4][4] = {};
  const int kend = (mt/2 + 1)*256;
  for (int k0 = 0; k0 < kend; k0 += 32){
    __syncthreads();
    #pragma unroll
    for (int p = 0; p < 2; ++p){
      const int c   = tid + p*256;
      const int row = c >> 2, kq = c & 3;
      const unsigned short* ga = Ab + ((size_t)row*SS + k0 + kq*8);
      const unsigned short* gb = Bb + ((size_t)row*SS + k0 + kq*8);
      const int lbase = w*1024 + p*4096;
      __builtin_amdgcn_global_load_lds(
          (const __attribute__((address_space(1))) void*)ga,
          (__attribute__((address_space(3))) void*)((char*)tA + lbase), 16, 0, 0);
      __builtin_amdgcn_global_load_lds(
          (const __attribute__((address_space(1))) void*)gb,
          (__attribute__((address_space(3))) void*)((char*)tB + lbase), 16, 0, 0);
    }
    __syncthreads();
    bf16x8 af[4], bfr[4];
    #pragma unroll
    for (int mi = 0; mi < 4; ++mi){
      const int r = wr*64 + mi*16 + lc;
      af[mi] = *reinterpret_cast<const bf16x8*>((const char*)tA + r*64 + lr*16);
    }
    #pragma unroll
    for (int ni = 0; ni < 4; ++ni){
      const int r = wc*64 + ni*16 + lc;
      bfr[ni] = *reinterpret_cast<const bf16x8*>((const char*)tB + r*64 + lr*16);
    }
    #pragma unroll
    for (int mi = 0; mi < 4; ++mi)
      #pragma unroll
      for (int ni = 0; ni < 4; ++ni)
        acc[mi][ni] = mfma16(af[mi], bfr[ni], acc[mi][ni]);
  }

  #pragma unroll
  for (int mi = 0; mi < 4; ++mi){
    #pragma unroll
    for (int i = 0; i < 4; ++i){
      const int row = m0 + wr*64 + mi*16 + lr*4 + i;
      const float linv = 1.0f / lfin[b*SS + row];
      #pragma unroll
      for (int ni = 0; ni < 4; ++ni){
        const int col = n0 + wc*64 + ni*16 + lc;
        out[(size_t)(b*SS + row)*DM + col] = acc[mi][ni][i]*linv;
      }
    }
  }
}

// ---------------- launcher ----------------
extern "C" void kernel_launch(void* const* d_in, const int* in_sizes, int n_in,
                              void* d_out, int out_size, void* d_ws, size_t ws_size,
                              hipStream_t stream)
{
  const float* x  = (const float*)d_in[0];
  const float* wq = (const float*)d_in[1];
  const float* bq = (const float*)d_in[2];
  const float* wk = (const float*)d_in[3];
  const float* bk = (const float*)d_in[4];
  const float* wv = (const float*)d_in[5];
  const float* bv = (const float*)d_in[6];
  float* out = (float*)d_out;

  char* ws = (char*)d_ws;
  unsigned short* xh  = (unsigned short*)(ws + 0);          // 16,777,216
  unsigned short* xl  = (unsigned short*)(ws + 16777216);   // 16,777,216
  unsigned short* Pbuf= (unsigned short*)(ws + 0);          // 33,554,432 (alias)
  unsigned short* Whi = (unsigned short*)(ws + 33554432);   //  2,359,296
  unsigned short* Wlo = (unsigned short*)(ws + 35913728);   //    262,144
  float* bias_all     = (float*)(ws + 36175872);            //      4,608
  unsigned short* Qh  = (unsigned short*)(ws + 36180480);   //  1,048,576
  unsigned short* Ql  = (unsigned short*)(ws + 37229056);   //  1,048,576
  unsigned short* Kh  = (unsigned short*)(ws + 38277632);   //  1,048,576
  unsigned short* Kl  = (unsigned short*)(ws + 39326208);   //  1,048,576
  unsigned short* Vt  = (unsigned short*)(ws + 40374784);   // 16,777,216
  float* Mrow         = (float*)(ws + 57152000);            //     32,768
  float* lpart        = (float*)(ws + 57184768);            //    262,144
  float* lfin         = (float*)(ws + 57446912);            //     32,768
  const size_t QKPART_OFF = 57479680;
  float* QKpart       = (float*)(ws + QKPART_OFF);          // 12,582,912
  const size_t NEED = QKPART_OFF + (size_t)3*MROWS*128*4;   // 70,062,592

  hipLaunchKernelGGL(prep_x_kernel, dim3(2048), dim3(256), 0, stream, x, xh, xl);
  hipLaunchKernelGGL(prep_w_kernel, dim3(1184), dim3(256), 0, stream,
                     wq, wk, wv, bq, bk, bv, Whi, Wlo, bias_all);
  if (ws_size >= NEED){
    hipLaunchKernelGGL(qkv_split_kernel, dim3(704), dim3(256), 0, stream,
                       xh, xl, Whi, Wlo, bias_all, Vt, QKpart);
    hipLaunchKernelGGL(qk_combine_kernel, dim3(1024), dim3(256), 0, stream,
                       QKpart, bias_all, Qh, Ql, Kh, Kl);
  } else {
    hipLaunchKernelGGL(qkv_gemm_kernel, dim3(576), dim3(256), 0, stream,
                       xh, xl, Whi, Wlo, bias_all, Qh, Ql, Kh, Kl, Vt);
  }
  hipLaunchKernelGGL(diag_kernel, dim3(32), dim3(256), 0, stream,
                     Qh, Ql, Kh, Kl, Mrow, lpart);
  hipLaunchKernelGGL(scores_kernel, dim3(288, 4), dim3(512), 0, stream,
                     Qh, Ql, Kh, Kl, Mrow, Pbuf, lpart);
  hipLaunchKernelGGL(combine_kernel, dim3(32), dim3(256), 0, stream, lpart, lfin);
  hipLaunchKernelGGL(pv_kernel, dim3(512), dim3(256), 0, stream, Pbuf, Vt, lfin, out);
}

// Round 6
// 140.227 us; speedup vs baseline: 1.6899x; 1.0887x over previous
//
#include <hip/hip_runtime.h>
#include <cstdint>
#include <cstddef>

// Problem constants
#define NB 4
#define SS 2048
#define DM 1024
#define DH 64
#define MROWS (NB*SS)      // 8192
#define NALL  (2*DH + DM)  // 1152

typedef __attribute__((ext_vector_type(8))) short bf16x8;
typedef __attribute__((ext_vector_type(4))) float f32x4;
typedef __attribute__((ext_vector_type(4))) unsigned short us4;

__device__ __forceinline__ unsigned short f2bf(float f){
  unsigned u = __builtin_bit_cast(unsigned, f);
  u = (u + 0x7fffu + ((u >> 16) & 1u)) >> 16;   // RNE
  return (unsigned short)u;
}
__device__ __forceinline__ float bf2f(unsigned short h){
  unsigned u = ((unsigned)h) << 16;
  return __builtin_bit_cast(float, u);
}
__device__ __forceinline__ f32x4 mfma16(bf16x8 a, bf16x8 b, f32x4 c){
  return __builtin_amdgcn_mfma_f32_16x16x32_bf16(a, b, c, 0, 0, 0);
}

// ---------------- prep: split x into bf16 hi/lo ----------------
__global__ void prep_x_kernel(const float* __restrict__ x,
                              unsigned short* __restrict__ xh,
                              unsigned short* __restrict__ xl){
  const int n4 = MROWS*DM/4;
  for (int i = blockIdx.x*blockDim.x + threadIdx.x; i < n4; i += gridDim.x*blockDim.x){
    float4 v = reinterpret_cast<const float4*>(x)[i];
    float f[4] = {v.x, v.y, v.z, v.w};
    us4 h, lo;
    #pragma unroll
    for (int j = 0; j < 4; ++j){
      unsigned short hh = f2bf(f[j]);
      h[j]  = hh;
      lo[j] = f2bf(f[j] - bf2f(hh));
    }
    reinterpret_cast<us4*>(xh)[i] = h;
    reinterpret_cast<us4*>(xl)[i] = lo;
  }
}

// ---------------- prep: weights + bias ----------------
__global__ void prep_w_kernel(const float* __restrict__ wq, const float* __restrict__ wk,
                              const float* __restrict__ wv,
                              const float* __restrict__ bq, const float* __restrict__ bk,
                              const float* __restrict__ bv,
                              unsigned short* __restrict__ Whi, unsigned short* __restrict__ Wlo,
                              float* __restrict__ bias_all){
  const int n = NALL*DM;
  for (int i = blockIdx.x*blockDim.x + threadIdx.x; i < n; i += gridDim.x*blockDim.x){
    const int r = i >> 10, c = i & 1023;
    float v;
    if (r < 64)       v = wq[r*1024 + c];
    else if (r < 128) v = wk[(r-64)*1024 + c];
    else              v = wv[(r-128)*1024 + c];
    const unsigned short h = f2bf(v);
    Whi[i] = h;
    if (r < 128) Wlo[i] = f2bf(v - bf2f(h));
    if (i < NALL) bias_all[i] = (i < 64) ? bq[i] : (i < 128) ? bk[i-64] : bv[i-128];
  }
}

// Stage one 128x32 A-tile + 128x32 B-tile into LDS buffer (4 gload_lds / thread).
#define STAGE_TILES(TAbuf, TBbuf, ABASE, BBASE, ASTRIDE, BSTRIDE, K0) do{        \
    _Pragma("unroll")                                                            \
    for (int p_ = 0; p_ < 2; ++p_){                                              \
      const int c_ = tid + p_*256;                                               \
      const int row_ = c_ >> 2, kq_ = c_ & 3;                                    \
      const int lbase_ = w*1024 + p_*4096;                                       \
      __builtin_amdgcn_global_load_lds(                                          \
        (const __attribute__((address_space(1))) void*)((ABASE) + ((size_t)row_*(ASTRIDE) + (K0) + kq_*8)), \
        (__attribute__((address_space(3))) void*)((char*)(TAbuf) + lbase_), 16, 0, 0); \
      __builtin_amdgcn_global_load_lds(                                          \
        (const __attribute__((address_space(1))) void*)((BBASE) + ((size_t)row_*(BSTRIDE) + (K0) + kq_*8)), \
        (__attribute__((address_space(3))) void*)((char*)(TBbuf) + lbase_), 16, 0, 0); \
    } }while(0)

// ---------------- QKV GEMM, split-K balanced + XCD-clustered + 2-phase dbuf ----------------
// 704 blocks = 64 mtiles x 11 equal jobs; XCD x owns mtiles [8x,8x+8) (L2 locality).
//   j 0..7  : V ntile j   -> Vt (bias fused)
//   j 8..10 : QK pass j-8 -> f32 partial QKpart[p]  (p0=xh.Whi, p1=xh.Wlo, p2=xl.Whi)
// K-loop: double-buffered LDS, prefetch next tile before computing current,
// counted vmcnt(4) + raw s_barrier (no vmcnt(0) drain in steady state).
__global__ __launch_bounds__(256) void qkv_split_kernel(
    const unsigned short* __restrict__ xh, const unsigned short* __restrict__ xl,
    const unsigned short* __restrict__ Whi, const unsigned short* __restrict__ Wlo,
    const float* __restrict__ bias_all,
    unsigned short* __restrict__ Vt, float* __restrict__ QKpart)
{
  __shared__ unsigned short tA[2][128*32];   // 2 x 8 KB
  __shared__ unsigned short tB[2][128*32];
  const int bx = blockIdx.x;
  const int xcd  = bx & 7;
  const int slot = bx >> 3;              // 0..87
  const int mtile = xcd*8 + (slot & 7);
  const int j = slot >> 3;               // 0..10
  const int m0 = mtile*128;
  const int tid = threadIdx.x;
  const int l = tid & 63, w = tid >> 6;
  const int lr = l >> 4, lc = l & 15;
  const int wr = w >> 1, wc = w & 1;

  const unsigned short* Ab;
  const unsigned short* Bb;
  if (j < 8){ Ab = xh; Bb = Whi + (size_t)(j+1)*128*DM; }
  else {
    const int p = j - 8;
    Ab = (p == 2) ? xl : xh;
    Bb = (p == 1) ? Wlo : Whi;
  }
  const unsigned short* Abase = Ab + (size_t)m0*DM;

  f32x4 acc[4][4] = {};
  STAGE_TILES(tA[0], tB[0], Abase, Bb, DM, DM, 0);
  for (int t = 0; t < 32; ++t){
    const int cur = t & 1;
    if (t + 1 < 32){
      STAGE_TILES(tA[cur^1], tB[cur^1], Abase, Bb, DM, DM, (t+1)*32);
      asm volatile("s_waitcnt vmcnt(4)" ::: "memory");
    } else {
      asm volatile("s_waitcnt vmcnt(0)" ::: "memory");
    }
    __builtin_amdgcn_s_barrier();
    bf16x8 af[4], bfr[4];
    #pragma unroll
    for (int mi = 0; mi < 4; ++mi){
      const int r = wr*64 + mi*16 + lc;
      af[mi] = *reinterpret_cast<const bf16x8*>((const char*)tA[cur] + r*64 + lr*16);
    }
    #pragma unroll
    for (int ni = 0; ni < 4; ++ni){
      const int r = wc*64 + ni*16 + lc;
      bfr[ni] = *reinterpret_cast<const bf16x8*>((const char*)tB[cur] + r*64 + lr*16);
    }
    #pragma unroll
    for (int mi = 0; mi < 4; ++mi)
      #pragma unroll
      for (int ni = 0; ni < 4; ++ni)
        acc[mi][ni] = mfma16(af[mi], bfr[ni], acc[mi][ni]);
    __builtin_amdgcn_sched_barrier(0);
    __builtin_amdgcn_s_barrier();
  }

  if (j < 8){
    const int n0 = (j+1)*128;
    #pragma unroll
    for (int ni = 0; ni < 4; ++ni){
      const int col = n0 + wc*64 + ni*16 + lc;
      const float bias = bias_all[col];
      const int vc = col - 128;
      #pragma unroll
      for (int mi = 0; mi < 4; ++mi){
        const int rowb = m0 + wr*64 + mi*16 + lr*4;
        const int b  = rowb >> 11;
        const int s  = rowb & 2047;
        us4 pk;
        #pragma unroll
        for (int i = 0; i < 4; ++i) pk[i] = f2bf(acc[mi][ni][i] + bias);
        *reinterpret_cast<us4*>(&Vt[((size_t)b*DM + vc)*SS + s]) = pk;
      }
    }
  } else {
    float* dst = QKpart + (size_t)(j-8)*MROWS*128;
    #pragma unroll
    for (int mi = 0; mi < 4; ++mi)
      #pragma unroll
      for (int i = 0; i < 4; ++i){
        const int row = m0 + wr*64 + mi*16 + lr*4 + i;
        #pragma unroll
        for (int ni = 0; ni < 4; ++ni){
          const int col = wc*64 + ni*16 + lc;
          dst[(size_t)row*128 + col] = acc[mi][ni][i];
        }
      }
  }
}

// ---------------- combine the 3 QK partials -> Qh/Ql/Kh/Kl ----------------
__global__ __launch_bounds__(256) void qk_combine_kernel(
    const float* __restrict__ QKpart, const float* __restrict__ bias_all,
    unsigned short* __restrict__ Qh, unsigned short* __restrict__ Ql,
    unsigned short* __restrict__ Kh, unsigned short* __restrict__ Kl)
{
  const int t = blockIdx.x*256 + threadIdx.x;    // 0..262143 -> (row, c4)
  const int row = t >> 5, c4 = t & 31;
  const int col0 = c4*4;
  us4 h, lo;
  #pragma unroll
  for (int i = 0; i < 4; ++i){
    const int col = col0 + i;
    const size_t o = (size_t)row*128 + col;
    float s = QKpart[o] + QKpart[(size_t)MROWS*128 + o]
            + QKpart[(size_t)2*MROWS*128 + o] + bias_all[col];
    const unsigned short hh = f2bf(s);
    h[i]  = hh;
    lo[i] = f2bf(s - bf2f(hh));
  }
  if (col0 < 64){
    *reinterpret_cast<us4*>(&Qh[(size_t)row*DH + col0]) = h;
    *reinterpret_cast<us4*>(&Ql[(size_t)row*DH + col0]) = lo;
  } else {
    *reinterpret_cast<us4*>(&Kh[(size_t)row*DH + col0 - 64]) = h;
    *reinterpret_cast<us4*>(&Kl[(size_t)row*DH + col0 - 64]) = lo;
  }
}

// ---------------- QKV GEMM fallback (3-pass, used only if ws too small) ----------------
__global__ __launch_bounds__(256) void qkv_gemm_kernel(
    const unsigned short* __restrict__ xh, const unsigned short* __restrict__ xl,
    const unsigned short* __restrict__ Whi, const unsigned short* __restrict__ Wlo,
    const float* __restrict__ bias_all,
    unsigned short* __restrict__ Qh, unsigned short* __restrict__ Ql,
    unsigned short* __restrict__ Kh, unsigned short* __restrict__ Kl,
    unsigned short* __restrict__ Vt)
{
  __shared__ unsigned short tA[128*32];
  __shared__ unsigned short tB[128*32];
  const int bx = blockIdx.x;
  const int mtile = bx & 63;
  const int ntile = bx >> 6;
  const int m0 = mtile*128, n0 = ntile*128;
  const int tid = threadIdx.x;
  const int l = tid & 63, w = tid >> 6;
  const int lr = l >> 4, lc = l & 15;
  const int wr = w >> 1, wc = w & 1;

  f32x4 acc[4][4] = {};
  const int npass = (ntile == 0) ? 3 : 1;
  for (int pass = 0; pass < npass; ++pass){
    const unsigned short* Ab = (pass == 2) ? xl : xh;
    const unsigned short* Bb = (pass == 1) ? Wlo : (Whi + (size_t)n0*DM);
    for (int k0 = 0; k0 < DM; k0 += 32){
      __syncthreads();
      #pragma unroll
      for (int p = 0; p < 2; ++p){
        const int c   = tid + p*256;
        const int row = c >> 2, kq = c & 3;
        const unsigned short* ga = Ab + ((size_t)(m0+row)*DM + k0 + kq*8);
        const unsigned short* gb = Bb + ((size_t)row*DM     + k0 + kq*8);
        const int lbase = w*1024 + p*4096;
        __builtin_amdgcn_global_load_lds(
            (const __attribute__((address_space(1))) void*)ga,
            (__attribute__((address_space(3))) void*)((char*)tA + lbase), 16, 0, 0);
        __builtin_amdgcn_global_load_lds(
            (const __attribute__((address_space(1))) void*)gb,
            (__attribute__((address_space(3))) void*)((char*)tB + lbase), 16, 0, 0);
      }
      __syncthreads();
      bf16x8 af[4], bfr[4];
      #pragma unroll
      for (int mi = 0; mi < 4; ++mi){
        const int r = wr*64 + mi*16 + lc;
        af[mi] = *reinterpret_cast<const bf16x8*>((const char*)tA + r*64 + lr*16);
      }
      #pragma unroll
      for (int ni = 0; ni < 4; ++ni){
        const int r = wc*64 + ni*16 + lc;
        bfr[ni] = *reinterpret_cast<const bf16x8*>((const char*)tB + r*64 + lr*16);
      }
      #pragma unroll
      for (int mi = 0; mi < 4; ++mi)
        #pragma unroll
        for (int ni = 0; ni < 4; ++ni)
          acc[mi][ni] = mfma16(af[mi], bfr[ni], acc[mi][ni]);
    }
  }

  #pragma unroll
  for (int ni = 0; ni < 4; ++ni){
    const int col = n0 + wc*64 + ni*16 + lc;
    const float bias = bias_all[col];
    #pragma unroll
    for (int mi = 0; mi < 4; ++mi){
      const int rowb = m0 + wr*64 + mi*16 + lr*4;
      if (ntile > 0){
        const int vc = col - 128;
        const int b  = rowb >> 11;
        const int s  = rowb & 2047;
        us4 pk;
        #pragma unroll
        for (int i = 0; i < 4; ++i) pk[i] = f2bf(acc[mi][ni][i] + bias);
        *reinterpret_cast<us4*>(&Vt[((size_t)b*DM + vc)*SS + s]) = pk;
      } else {
        #pragma unroll
        for (int i = 0; i < 4; ++i){
          const int row = rowb + i;
          const float v = acc[mi][ni][i] + bias;
          const unsigned short h   = f2bf(v);
          const unsigned short lo2 = f2bf(v - bf2f(h));
          if (col < DH){
            Qh[(size_t)row*DH + col] = h;
            Ql[(size_t)row*DH + col] = lo2;
          } else {
            Kh[(size_t)row*DH + col - DH] = h;
            Kl[(size_t)row*DH + col - DH] = lo2;
          }
        }
      }
    }
  }
}

// ---------------- diag: per-row softmax anchor M_r = q_r.k_r + 20, zero lpart ----------------
__global__ __launch_bounds__(256) void diag_kernel(
    const unsigned short* __restrict__ Qh, const unsigned short* __restrict__ Ql,
    const unsigned short* __restrict__ Kh, const unsigned short* __restrict__ Kl,
    float* __restrict__ Mrow, float* __restrict__ lpart)
{
  const int r = blockIdx.x*256 + threadIdx.x;   // 0..8191
  float dot = 0.f;
  #pragma unroll
  for (int c = 0; c < 8; ++c){
    bf16x8 a  = *reinterpret_cast<const bf16x8*>(Qh + (size_t)r*DH + c*8);
    bf16x8 al = *reinterpret_cast<const bf16x8*>(Ql + (size_t)r*DH + c*8);
    bf16x8 bh = *reinterpret_cast<const bf16x8*>(Kh + (size_t)r*DH + c*8);
    bf16x8 bl = *reinterpret_cast<const bf16x8*>(Kl + (size_t)r*DH + c*8);
    #pragma unroll
    for (int j = 0; j < 8; ++j)
      dot += (bf2f((unsigned short)a[j]) + bf2f((unsigned short)al[j])) *
             (bf2f((unsigned short)bh[j]) + bf2f((unsigned short)bl[j]));
  }
  Mrow[r] = dot + 20.0f;
  #pragma unroll
  for (int kc = 0; kc < 8; ++kc) lpart[(size_t)r*8 + kc] = 0.f;
}

// ---------------- scores: P = exp(S - M_r) bf16, per-chunk row sums ----------------
__global__ __launch_bounds__(512) void scores_kernel(
    const unsigned short* __restrict__ Qh, const unsigned short* __restrict__ Ql,
    const unsigned short* __restrict__ Kh, const unsigned short* __restrict__ Kl,
    const float* __restrict__ Mrow,
    unsigned short* __restrict__ Pbuf, float* __restrict__ lpart)
{
  __shared__ float ws_s[8][32];
  const int t = blockIdx.x, b = blockIdx.y;
  int g = 0;
  while (g < 7 && 4*(g+1)*(g+2) <= t) ++g;
  const int base = 4*g*(g+1);
  const int qt = 8*g + (t - base)/(g+1);
  const int kc = (t - base)%(g+1);
  const int q0 = qt*32, kbase = kc*256;
  const int tid = threadIdx.x, l = tid & 63, w = tid >> 6;
  const int lr = l >> 4, lc = l & 15;
  const int kw0 = kbase + w*32;
  const float L2E = 1.4426950408889634f;

  bf16x8 qh[2][2], qlo[2][2], kh[2][2], kl2[2][2];
  #pragma unroll
  for (int qi = 0; qi < 2; ++qi)
    #pragma unroll
    for (int ks = 0; ks < 2; ++ks){
      const size_t off = (size_t)(b*SS + q0 + qi*16 + lc)*DH + ks*32 + lr*8;
      qh[qi][ks]  = *reinterpret_cast<const bf16x8*>(&Qh[off]);
      qlo[qi][ks] = *reinterpret_cast<const bf16x8*>(&Ql[off]);
    }
  #pragma unroll
  for (int ki = 0; ki < 2; ++ki)
    #pragma unroll
    for (int ks = 0; ks < 2; ++ks){
      const size_t off = (size_t)(b*SS + kw0 + ki*16 + lc)*DH + ks*32 + lr*8;
      kh[ki][ks]  = *reinterpret_cast<const bf16x8*>(&Kh[off]);
      kl2[ki][ks] = *reinterpret_cast<const bf16x8*>(&Kl[off]);
    }

  f32x4 sa[2][2] = {};
  #pragma unroll
  for (int qi = 0; qi < 2; ++qi)
    #pragma unroll
    for (int ki = 0; ki < 2; ++ki)
      #pragma unroll
      for (int ks = 0; ks < 2; ++ks){
        sa[qi][ki] = mfma16(qh[qi][ks],  kh[ki][ks],  sa[qi][ki]);
        sa[qi][ki] = mfma16(qh[qi][ks],  kl2[ki][ks], sa[qi][ki]);
        sa[qi][ki] = mfma16(qlo[qi][ks], kh[ki][ks],  sa[qi][ki]);
      }

  float Mv[2][4];
  #pragma unroll
  for (int qi = 0; qi < 2; ++qi)
    #pragma unroll
    for (int i = 0; i < 4; ++i)
      Mv[qi][i] = Mrow[b*SS + q0 + qi*16 + lr*4 + i];

  const bool diagblk = (kc == (qt >> 3));
  float psum[2][4] = {};
  #pragma unroll
  for (int qi = 0; qi < 2; ++qi)
    #pragma unroll
    for (int ki = 0; ki < 2; ++ki)
      #pragma unroll
      for (int i = 0; i < 4; ++i){
        const int qrow = qi*16 + lr*4 + i;
        const int kcol = w*32 + ki*16 + lc;
        float p;
        if (diagblk && (kbase + kcol > q0 + qrow)) p = 0.f;
        else p = exp2f((sa[qi][ki][i] - Mv[qi][i])*L2E);
        Pbuf[(size_t)(b*SS + q0 + qrow)*SS + kbase + kcol] = f2bf(p);
        psum[qi][i] += p;
      }

  #pragma unroll
  for (int qi = 0; qi < 2; ++qi)
    #pragma unroll
    for (int i = 0; i < 4; ++i){
      float s = psum[qi][i];
      #pragma unroll
      for (int m = 1; m < 16; m <<= 1) s += __shfl_xor(s, m);
      psum[qi][i] = s;
    }
  if (lc == 0){
    #pragma unroll
    for (int qi = 0; qi < 2; ++qi)
      #pragma unroll
      for (int i = 0; i < 4; ++i)
        ws_s[w][qi*16 + lr*4 + i] = psum[qi][i];
  }
  __syncthreads();
  if (tid < 32){
    float s = 0.f;
    #pragma unroll
    for (int w2 = 0; w2 < 8; ++w2) s += ws_s[w2][tid];
    lpart[(size_t)(b*SS + q0 + tid)*8 + kc] = s;
  }
}

// ---------------- combine: l_r = sum of chunk partials ----------------
__global__ __launch_bounds__(256) void combine_kernel(const float* __restrict__ lpart,
                                                      float* __restrict__ lfin){
  const int r = blockIdx.x*256 + threadIdx.x;
  float s = 0.f;
  #pragma unroll
  for (int kc = 0; kc < 8; ++kc) s += lpart[(size_t)r*8 + kc];
  lfin[r] = s;
}

// ---------------- PV GEMM + XCD-clustered + 2-phase dbuf: out = (P @ V) / l ----------------
// 512 blocks = 64 per XCD; XCD x owns (batch = x>>1, nt-group = x&1); within-XCD
// mt paired k/(15-k) per CU. kend = (mt/2+1)*256 covers every row's diagonal
// chunk (masked region zero-filled by scores_kernel).
__global__ __launch_bounds__(256) void pv_kernel(
    const unsigned short* __restrict__ Pbuf, const unsigned short* __restrict__ Vt,
    const float* __restrict__ lfin, float* __restrict__ out)
{
  __shared__ unsigned short tA[2][128*32];
  __shared__ unsigned short tB[2][128*32];
  const int bx = blockIdx.x;           // 0..511
  const int xcd  = bx & 7;
  const int slot = bx >> 3;            // 0..63
  const int b   = xcd >> 1;
  const int ntg = xcd & 1;
  const int nt  = ntg*4 + (slot & 3);
  const int mt  = (slot < 32) ? (15 - (slot >> 2)) : ((slot - 32) >> 2);
  const int m0 = mt*128, n0 = nt*128;
  const int tid = threadIdx.x;
  const int l = tid & 63, w = tid >> 6;
  const int lr = l >> 4, lc = l & 15;
  const int wr = w >> 1, wc = w & 1;

  const unsigned short* Ab = Pbuf + (size_t)(b*SS + m0)*SS;
  const unsigned short* Bb = Vt   + (size_t)(b*DM + n0)*SS;

  f32x4 acc[4][4] = {};
  const int NT = (mt/2 + 1)*8;         // k-steps of 32
  STAGE_TILES(tA[0], tB[0], Ab, Bb, SS, SS, 0);
  for (int t = 0; t < NT; ++t){
    const int cur = t & 1;
    if (t + 1 < NT){
      STAGE_TILES(tA[cur^1], tB[cur^1], Ab, Bb, SS, SS, (t+1)*32);
      asm volatile("s_waitcnt vmcnt(4)" ::: "memory");
    } else {
      asm volatile("s_waitcnt vmcnt(0)" ::: "memory");
    }
    __builtin_amdgcn_s_barrier();
    bf16x8 af[4], bfr[4];
    #pragma unroll
    for (int mi = 0; mi < 4; ++mi){
      const int r = wr*64 + mi*16 + lc;
      af[mi] = *reinterpret_cast<const bf16x8*>((const char*)tA[cur] + r*64 + lr*16);
    }
    #pragma unroll
    for (int ni = 0; ni < 4; ++ni){
      const int r = wc*64 + ni*16 + lc;
      bfr[ni] = *reinterpret_cast<const bf16x8*>((const char*)tB[cur] + r*64 + lr*16);
    }
    #pragma unroll
    for (int mi = 0; mi < 4; ++mi)
      #pragma unroll
      for (int ni = 0; ni < 4; ++ni)
        acc[mi][ni] = mfma16(af[mi], bfr[ni], acc[mi][ni]);
    __builtin_amdgcn_sched_barrier(0);
    __builtin_amdgcn_s_barrier();
  }

  #pragma unroll
  for (int mi = 0; mi < 4; ++mi){
    #pragma unroll
    for (int i = 0; i < 4; ++i){
      const int row = m0 + wr*64 + mi*16 + lr*4 + i;
      const float linv = 1.0f / lfin[b*SS + row];
      #pragma unroll
      for (int ni = 0; ni < 4; ++ni){
        const int col = n0 + wc*64 + ni*16 + lc;
        out[(size_t)(b*SS + row)*DM + col] = acc[mi][ni][i]*linv;
      }
    }
  }
}

// ---------------- launcher ----------------
extern "C" void kernel_launch(void* const* d_in, const int* in_sizes, int n_in,
                              void* d_out, int out_size, void* d_ws, size_t ws_size,
                              hipStream_t stream)
{
  const float* x  = (const float*)d_in[0];
  const float* wq = (const float*)d_in[1];
  const float* bq = (const float*)d_in[2];
  const float* wk = (const float*)d_in[3];
  const float* bk = (const float*)d_in[4];
  const float* wv = (const float*)d_in[5];
  const float* bv = (const float*)d_in[6];
  float* out = (float*)d_out;

  char* ws = (char*)d_ws;
  unsigned short* xh  = (unsigned short*)(ws + 0);          // 16,777,216
  unsigned short* xl  = (unsigned short*)(ws + 16777216);   // 16,777,216
  unsigned short* Pbuf= (unsigned short*)(ws + 0);          // 33,554,432 (alias)
  unsigned short* Whi = (unsigned short*)(ws + 33554432);   //  2,359,296
  unsigned short* Wlo = (unsigned short*)(ws + 35913728);   //    262,144
  float* bias_all     = (float*)(ws + 36175872);            //      4,608
  unsigned short* Qh  = (unsigned short*)(ws + 36180480);   //  1,048,576
  unsigned short* Ql  = (unsigned short*)(ws + 37229056);   //  1,048,576
  unsigned short* Kh  = (unsigned short*)(ws + 38277632);   //  1,048,576
  unsigned short* Kl  = (unsigned short*)(ws + 39326208);   //  1,048,576
  unsigned short* Vt  = (unsigned short*)(ws + 40374784);   // 16,777,216
  float* Mrow         = (float*)(ws + 57152000);            //     32,768
  float* lpart        = (float*)(ws + 57184768);            //    262,144
  float* lfin         = (float*)(ws + 57446912);            //     32,768
  const size_t QKPART_OFF = 57479680;
  float* QKpart       = (float*)(ws + QKPART_OFF);          // 12,582,912
  const size_t NEED = QKPART_OFF + (size_t)3*MROWS*128*4;   // 70,062,592

  hipLaunchKernelGGL(prep_x_kernel, dim3(2048), dim3(256), 0, stream, x, xh, xl);
  hipLaunchKernelGGL(prep_w_kernel, dim3(1184), dim3(256), 0, stream,
                     wq, wk, wv, bq, bk, bv, Whi, Wlo, bias_all);
  if (ws_size >= NEED){
    hipLaunchKernelGGL(qkv_split_kernel, dim3(704), dim3(256), 0, stream,
                       xh, xl, Whi, Wlo, bias_all, Vt, QKpart);
    hipLaunchKernelGGL(qk_combine_kernel, dim3(1024), dim3(256), 0, stream,
                       QKpart, bias_all, Qh, Ql, Kh, Kl);
  } else {
    hipLaunchKernelGGL(qkv_gemm_kernel, dim3(576), dim3(256), 0, stream,
                       xh, xl, Whi, Wlo, bias_all, Qh, Ql, Kh, Kl, Vt);
  }
  hipLaunchKernelGGL(diag_kernel, dim3(32), dim3(256), 0, stream,
                     Qh, Ql, Kh, Kl, Mrow, lpart);
  hipLaunchKernelGGL(scores_kernel, dim3(288, 4), dim3(512), 0, stream,
                     Qh, Ql, Kh, Kl, Mrow, Pbuf, lpart);
  hipLaunchKernelGGL(combine_kernel, dim3(32), dim3(256), 0, stream, lpart, lfin);
  hipLaunchKernelGGL(pv_kernel, dim3(512), dim3(256), 0, stream, Pbuf, Vt, lfin, out);
}